// Round 13
// baseline (540.472 us; speedup 1.0000x reference)
//
#include <hip/hip_runtime.h>
#include <math.h>

// ---------------------------------------------------------------------------
// GAT 3-layer pipeline — R11 body, DIAGNOSTIC build:
// k_dotc_mfma / L0 k_gather4 / L0 k_gemm_mfma are launched 3x each
// (idempotent) to measure their per-kernel time via the dur_us delta.
// ---------------------------------------------------------------------------

#define E0 375000
#define E1 90000
#define E2 10240
#define ETOT (E0 + E1 + E2)
#define ND0 25000
#define ND1 6000
#define ND2 1024
#define NTOT (ND0 + ND1 + ND2)   /* 32024 */
#define NCH ((NTOT + 127) / 128) /* 251 */

static const int L_NS[3]   = {150000, 25000, 6000};
static const int L_ND[3]   = {ND0, ND1, ND2};

typedef short bf8_t __attribute__((ext_vector_type(8)));
typedef float f32x4 __attribute__((ext_vector_type(4)));

__device__ __forceinline__ float lrelu(float v) { return v >= 0.f ? v : 0.2f * v; }
__device__ __forceinline__ unsigned short f2b(float f) {
  unsigned u = __float_as_uint(f);
  unsigned r = u + 0x7fffu + ((u >> 16) & 1u);
  return (unsigned short)(r >> 16);
}
__device__ __forceinline__ float b2f(unsigned v) {  // low 16 bits
  return __uint_as_float(v << 16);
}
__device__ __forceinline__ unsigned bpack(float a, float b) {
  return (unsigned)f2b(a) | ((unsigned)f2b(b) << 16);
}

__device__ __forceinline__ void gload16(const unsigned short* g, unsigned short* l) {
  __builtin_amdgcn_global_load_lds(
      (const __attribute__((address_space(1))) unsigned int*)g,
      (__attribute__((address_space(3))) unsigned int*)l, 16, 0, 0);
}

// ---------------- prologue (one-shot, topology/weights only) ----------------

__global__ void k_prep_count(
    const int* __restrict__ d0, const int* __restrict__ d1,
    const int* __restrict__ d2, int* __restrict__ cntAll, int* __restrict__ r,
    const float* __restrict__ Ws0, const float* __restrict__ Wd0,
    const float* __restrict__ al0, const float* __restrict__ ar0,
    const float* __restrict__ Ws1, const float* __restrict__ Wd1,
    const float* __restrict__ al1, const float* __restrict__ ar1,
    const float* __restrict__ Ws2, const float* __restrict__ Wd2,
    const float* __restrict__ al2, const float* __restrict__ ar2,
    unsigned short* __restrict__ wlrb, float* __restrict__ wlr1,
    float* __restrict__ wlr2,
    unsigned short* __restrict__ B0, unsigned short* __restrict__ B1,
    unsigned short* __restrict__ B2) {
  int gid = blockIdx.x * 256 + threadIdx.x;
  if (gid < ETOT) {
    int goff, dv;
    if (gid < E0) { goff = 0; dv = d0[gid]; }
    else if (gid < E0 + E1) { goff = ND0; dv = d1[gid - E0]; }
    else { goff = ND0 + ND1; dv = d2[gid - E0 - E1]; }
    r[gid] = atomicAdd(&cntAll[goff + dv], 1);
  }
  if (gid < 2048) {
    int h = gid >> 8, k = gid & 255;
    const float* W = (h < 4) ? Ws0 : Wd0;
    const float* a = (h < 4) ? al0 : ar0;
    int hh = h & 3;
    float acc = 0.f;
    for (int d = 0; d < 128; ++d)
      acc += a[hh * 128 + d] * W[(size_t)(hh * 128 + d) * 256 + k];
    wlrb[h * 264 + k] = f2b(acc);
  } else if (gid < 4096) {
    int idx = gid - 2048;
    wlrb[(8 + (idx >> 8)) * 264 + (idx & 255)] = 0;
  } else if (gid < 12288) {
    int idx = gid - 4096;
    float* wlr; const float *Ws, *Wd, *al, *ar; int Fout;
    if (idx < 4096) { wlr = wlr1; Ws = Ws1; Wd = Wd1; al = al1; ar = ar1; Fout = 128; }
    else { idx -= 4096; wlr = wlr2; Ws = Ws2; Wd = Wd2; al = al2; ar = ar2; Fout = 47; }
    int which = idx >> 11;
    int rem = idx & 2047;
    int h = rem >> 9, k = rem & 511;
    const float* W = which ? Wd : Ws;
    const float* a = which ? ar : al;
    float acc = 0.f;
    for (int d = 0; d < Fout; ++d)
      acc += a[h * Fout + d] * W[(size_t)(h * Fout + d) * 512 + k];
    wlr[which * 2048 + rem] = acc;
  }
  const int n0 = 512 * 256, n1 = 512 * 512, n2 = 188 * 512;
  for (int i = gid; i < n0 + n1 + n2; i += gridDim.x * 256) {
    if (i < n0) B0[i] = f2b(Ws0[i]);
    else if (i < n0 + n1) B1[i - n0] = f2b(Ws1[i - n0]);
    else B2[i - n0 - n1] = f2b(Ws2[i - n0 - n1]);
  }
}

__global__ __launch_bounds__(128) void k_scanA(const int* __restrict__ cnt,
                                               int* __restrict__ S,
                                               int* __restrict__ btot, int n) {
  __shared__ int wt[2];
  int c = blockIdx.x, t = threadIdx.x, lane = t & 63, w = t >> 6;
  int g = c * 128 + t;
  int v = (g < n) ? cnt[g] : 0;
  int incl = v;
  for (int off = 1; off < 64; off <<= 1) {
    int u = __shfl_up(incl, off);
    if (lane >= off) incl += u;
  }
  if (lane == 63) wt[w] = incl;
  __syncthreads();
  int base = (w == 1) ? wt[0] : 0;
  if (g < n) S[g] = incl - v + base;
  if (t == 127) btot[c] = wt[0] + wt[1];
}

__global__ __launch_bounds__(256) void k_scanB(const int* __restrict__ btot,
                                               int* __restrict__ S, int n, int etot) {
  __shared__ int tv[256];
  int c = blockIdx.x, t = threadIdx.x;
  int own = (t < NCH) ? btot[t] : 0;
  tv[t] = own;
  __syncthreads();
  for (int off = 1; off < 256; off <<= 1) {
    int u = (t >= off) ? tv[t - off] : 0;
    __syncthreads();
    tv[t] += u;
    __syncthreads();
  }
  int base = tv[c] - btot[c];
  int g = c * 128 + (t & 127);
  if (t < 128 && g < n) S[g] += base;
  if (c == 0 && t == 255) S[n] = etot;
}

__global__ void k_scatter_all(
    const int* __restrict__ s0, const int* __restrict__ d0,
    const int* __restrict__ s1, const int* __restrict__ d1,
    const int* __restrict__ s2, const int* __restrict__ d2,
    const int* __restrict__ S, const int* __restrict__ r,
    int* __restrict__ cvAll) {
  int g = blockIdx.x * 256 + threadIdx.x;
  if (g >= ETOT) return;
  int goff, dv, sv;
  if (g < E0) { goff = 0; dv = d0[g]; sv = s0[g]; }
  else if (g < E0 + E1) { int e = g - E0; goff = ND0; dv = d1[e]; sv = s1[e]; }
  else { int e = g - E0 - E1; goff = ND0 + ND1; dv = d2[e]; sv = s2[e]; }
  cvAll[S[goff + dv] + r[g]] = sv;
}

// ---------------- per-layer feature kernels ----------------

__global__ __launch_bounds__(256) void k_dotc_mfma(
    const float* __restrict__ x, const unsigned short* __restrict__ wlrb,
    float* __restrict__ ell, float* __restrict__ err, int Ns, int Nd) {
  __shared__ unsigned short As[128 * 72];
  __shared__ unsigned short Bs[16 * 264];
  const int tid = threadIdx.x;
  const int w = tid >> 6, lane = tid & 63;
  const int bm = blockIdx.x * 128;
  const int rowg = tid >> 4;
  const int seg  = tid & 15;
  for (int i = tid; i < 16 * 264; i += 256) Bs[i] = wlrb[i];
  f32x4 acc[2] = {};
  for (int k0 = 0; k0 < 256; k0 += 64) {
    __syncthreads();
#pragma unroll
    for (int i = 0; i < 8; ++i) {
      int row = rowg + i * 16;
      int gm = bm + row;
      int gmc = gm < Ns ? gm : Ns - 1;
      float4 a = *reinterpret_cast<const float4*>(x + (size_t)gmc * 256 + k0 + seg * 4);
      ushort4 ub;
      ub.x = f2b(a.x); ub.y = f2b(a.y); ub.z = f2b(a.z); ub.w = f2b(a.w);
      *reinterpret_cast<ushort4*>(&As[row * 72 + seg * 4]) = ub;
    }
    __syncthreads();
    const int ra = w * 32 + (lane & 15);
    const int kf = (lane >> 4) * 8;
#pragma unroll
    for (int ks = 0; ks < 2; ++ks) {
      bf8_t b0 = *reinterpret_cast<const bf8_t*>(&Bs[(lane & 15) * 264 + k0 + ks * 32 + kf]);
      bf8_t a0 = *reinterpret_cast<const bf8_t*>(&As[ra * 72 + ks * 32 + kf]);
      bf8_t a1 = *reinterpret_cast<const bf8_t*>(&As[(ra + 16) * 72 + ks * 32 + kf]);
      acc[0] = __builtin_amdgcn_mfma_f32_16x16x32_bf16(a0, b0, acc[0], 0, 0, 0);
      acc[1] = __builtin_amdgcn_mfma_f32_16x16x32_bf16(a1, b0, acc[1], 0, 0, 0);
    }
  }
  int col = lane & 15;
#pragma unroll
  for (int fm = 0; fm < 2; ++fm) {
#pragma unroll
    for (int j = 0; j < 4; ++j) {
      int node = bm + w * 32 + fm * 16 + (lane >> 4) * 4 + j;
      if (node >= Ns) continue;
      float v = acc[fm][j];
      if (col < 4) ell[(size_t)node * 4 + col] = v;
      else if (col < 8 && node < Nd) err[(size_t)node * 4 + (col - 4)] = v;
    }
  }
}

__device__ __forceinline__ void reduce8_store(float v[8], int lane, int node, int Nd,
                                              float* __restrict__ ell,
                                              float* __restrict__ err) {
#pragma unroll
  for (int h = 0; h < 8; ++h) {
    v[h] += __shfl_xor(v[h], 8);
    v[h] += __shfl_xor(v[h], 16);
    v[h] += __shfl_xor(v[h], 32);
  }
  int sel = lane >> 3;
  float t01 = (sel & 1) ? v[1] : v[0];
  float t23 = (sel & 1) ? v[3] : v[2];
  float t45 = (sel & 1) ? v[5] : v[4];
  float t67 = (sel & 1) ? v[7] : v[6];
  float t03 = (sel & 2) ? t23 : t01;
  float t47 = (sel & 2) ? t67 : t45;
  float s   = (sel & 4) ? t47 : t03;
  s += __shfl_xor(s, 1);
  s += __shfl_xor(s, 2);
  s += __shfl_xor(s, 4);
  if ((lane & 7) == 0) {
    if (sel < 4) ell[(size_t)node * 4 + sel] = s;
    else if (node < Nd) err[(size_t)node * 4 + (sel - 4)] = s;
  }
}

__global__ __launch_bounds__(256) void k_dot_bf(
    const unsigned short* __restrict__ Hs, const float* __restrict__ wlr,
    float* __restrict__ ell, float* __restrict__ err, int Ns, int Nd) {
  int node = blockIdx.x * 4 + (threadIdx.x >> 6);
  int lane = threadIdx.x & 63;
  if (node >= Ns) return;
  uint4 raw = *reinterpret_cast<const uint4*>(Hs + (size_t)node * 512 + lane * 8);
  float xv[8];
  xv[0] = b2f(raw.x & 0xffffu); xv[1] = b2f(raw.x >> 16);
  xv[2] = b2f(raw.y & 0xffffu); xv[3] = b2f(raw.y >> 16);
  xv[4] = b2f(raw.z & 0xffffu); xv[5] = b2f(raw.z >> 16);
  xv[6] = b2f(raw.w & 0xffffu); xv[7] = b2f(raw.w >> 16);
  bool nR = node < Nd;
  float v[8];
#pragma unroll
  for (int h = 0; h < 4; ++h) {
    const float* wp = wlr + h * 512 + lane * 8;
    float4 w0 = *reinterpret_cast<const float4*>(wp);
    float4 w1 = *reinterpret_cast<const float4*>(wp + 4);
    v[h] = xv[0]*w0.x + xv[1]*w0.y + xv[2]*w0.z + xv[3]*w0.w +
           xv[4]*w1.x + xv[5]*w1.y + xv[6]*w1.z + xv[7]*w1.w;
    v[4 + h] = 0.f;
    if (nR) {
      const float* wq = wlr + 2048 + h * 512 + lane * 8;
      float4 u0 = *reinterpret_cast<const float4*>(wq);
      float4 u1 = *reinterpret_cast<const float4*>(wq + 4);
      v[4 + h] = xv[0]*u0.x + xv[1]*u0.y + xv[2]*u0.z + xv[3]*u0.w +
                 xv[4]*u1.x + xv[5]*u1.y + xv[6]*u1.z + xv[7]*u1.w;
    }
  }
  reduce8_store(v, lane, node, Nd, ell, err);
}

// Unified gather: one WAVE per dst node, 4 nodes per block, barrier-free.
template <int FIN, bool F32>
__global__ __launch_bounds__(256) void k_gather4(
    const void* __restrict__ Hv, const float* __restrict__ ell,
    const float* __restrict__ err, const int* __restrict__ rowptr,
    const int* __restrict__ colv, unsigned short* __restrict__ Z, int Nd) {
  constexpr int CPL = F32 ? 4 : 8;
  constexpr int CAP = 256;
  __shared__ float4 esm_all[4][CAP];
  __shared__ int csm_all[4][CAP];
  int w = threadIdx.x >> 6, lane = threadIdx.x & 63;
  int n = blockIdx.x * 4 + w;
  if (n >= Nd) return;
  float4* esm = esm_all[w];
  int* csm = csm_all[w];
  int beg = rowptr[n], cnt = rowptr[n + 1] - beg;
  float4 er4 = *reinterpret_cast<const float4*>(err + (size_t)n * 4);
  float m0 = -INFINITY, m1 = -INFINITY, m2 = -INFINITY, m3 = -INFINITY;
  for (int i = lane; i < cnt; i += 64) {
    int c = colv[beg + i];
    float4 el4 = *reinterpret_cast<const float4*>(ell + (size_t)c * 4);
    float4 e4;
    e4.x = lrelu(el4.x + er4.x); e4.y = lrelu(el4.y + er4.y);
    e4.z = lrelu(el4.z + er4.z); e4.w = lrelu(el4.w + er4.w);
    if (i < CAP) { csm[i] = c; esm[i] = e4; }
    m0 = fmaxf(m0, e4.x); m1 = fmaxf(m1, e4.y);
    m2 = fmaxf(m2, e4.z); m3 = fmaxf(m3, e4.w);
  }
  for (int off = 32; off > 0; off >>= 1) {
    m0 = fmaxf(m0, __shfl_xor(m0, off));
    m1 = fmaxf(m1, __shfl_xor(m1, off));
    m2 = fmaxf(m2, __shfl_xor(m2, off));
    m3 = fmaxf(m3, __shfl_xor(m3, off));
  }
  __builtin_amdgcn_sched_barrier(0);
  float s0 = 0.f, s1 = 0.f, s2 = 0.f, s3 = 0.f;
  float acc[4][CPL] = {};

  auto loadrow = [&](int c, float xv[CPL]) {
    if constexpr (F32) {
      float4 a = *reinterpret_cast<const float4*>(
          (const float*)Hv + (size_t)c * FIN + lane * 4);
      xv[0] = a.x; xv[1] = a.y; xv[2] = a.z; xv[3] = a.w;
    } else {
      uint4 raw = *reinterpret_cast<const uint4*>(
          (const unsigned short*)Hv + (size_t)c * FIN + lane * 8);
      xv[0] = b2f(raw.x & 0xffffu); xv[1] = b2f(raw.x >> 16);
      xv[2] = b2f(raw.y & 0xffffu); xv[3] = b2f(raw.y >> 16);
      xv[4] = b2f(raw.z & 0xffffu); xv[5] = b2f(raw.z >> 16);
      xv[6] = b2f(raw.w & 0xffffu); xv[7] = b2f(raw.w >> 16);
    }
  };
  auto accum = [&](float4 w4, const float xv[CPL]) {
    s0 += w4.x; s1 += w4.y; s2 += w4.z; s3 += w4.w;
#pragma unroll
    for (int c2 = 0; c2 < CPL; ++c2) {
      acc[0][c2] = fmaf(w4.x, xv[c2], acc[0][c2]);
      acc[1][c2] = fmaf(w4.y, xv[c2], acc[1][c2]);
      acc[2][c2] = fmaf(w4.z, xv[c2], acc[2][c2]);
      acc[3][c2] = fmaf(w4.w, xv[c2], acc[3][c2]);
    }
  };

  if (cnt <= CAP) {
    for (int i = lane; i < cnt; i += 64) {
      float4 e = esm[i];
      esm[i] = make_float4(__expf(e.x - m0), __expf(e.y - m1),
                           __expf(e.z - m2), __expf(e.w - m3));
    }
    __builtin_amdgcn_sched_barrier(0);
    int j = 0;
    for (; j + 2 <= cnt; j += 2) {
      int c0 = csm[j], c1 = csm[j + 1];
      float4 wa = esm[j], wb = esm[j + 1];
      float xa[CPL], xb[CPL];
      loadrow(c0, xa);
      loadrow(c1, xb);
      accum(wa, xa);
      accum(wb, xb);
    }
    if (j < cnt) {
      float xa[CPL];
      loadrow(csm[j], xa);
      accum(esm[j], xa);
    }
  } else {
    for (int j = 0; j < cnt; ++j) {
      int c = colv[beg + j];
      float4 el4 = *reinterpret_cast<const float4*>(ell + (size_t)c * 4);
      float4 w4;
      w4.x = __expf(lrelu(el4.x + er4.x) - m0);
      w4.y = __expf(lrelu(el4.y + er4.y) - m1);
      w4.z = __expf(lrelu(el4.z + er4.z) - m2);
      w4.w = __expf(lrelu(el4.w + er4.w) - m3);
      float xa[CPL];
      loadrow(c, xa);
      accum(w4, xa);
    }
  }
  float inv[4];
  inv[0] = 1.f / fmaxf(s0, 1e-9f); inv[1] = 1.f / fmaxf(s1, 1e-9f);
  inv[2] = 1.f / fmaxf(s2, 1e-9f); inv[3] = 1.f / fmaxf(s3, 1e-9f);
#pragma unroll
  for (int h = 0; h < 4; ++h) {
    if constexpr (F32) {
      ushort4 o;
      o.x = f2b(acc[h][0] * inv[h]); o.y = f2b(acc[h][1] * inv[h]);
      o.z = f2b(acc[h][2] * inv[h]); o.w = f2b(acc[h][3] * inv[h]);
      *reinterpret_cast<ushort4*>(Z + (size_t)n * 4 * FIN + h * FIN + lane * 4) = o;
    } else {
      uint4 o;
      o.x = bpack(acc[h][0] * inv[h], acc[h][1] * inv[h]);
      o.y = bpack(acc[h][2] * inv[h], acc[h][3] * inv[h]);
      o.z = bpack(acc[h][4] * inv[h], acc[h][5] * inv[h]);
      o.w = bpack(acc[h][6] * inv[h], acc[h][7] * inv[h]);
      *reinterpret_cast<uint4*>(Z + (size_t)n * 4 * FIN + h * FIN + lane * 8) = o;
    }
  }
}

// bf16 MFMA GEMM (unchanged, proven)
template <int BN, bool ACT, bool OUTBF>
__global__ __launch_bounds__(256) void k_gemm_mfma(
    const unsigned short* __restrict__ Zb, const unsigned short* __restrict__ Wb,
    const float* __restrict__ bias, void* __restrict__ outv,
    int M, int N, int K) {
  constexpr int FN = BN / 16;
  constexpr int AI = 4;
  constexpr int BI = BN / 32;
  int h = blockIdx.z;
  __shared__ unsigned short As[128 * 64];
  __shared__ unsigned short Bs[BN * 64];
  const int tid = threadIdx.x;
  const int w = tid >> 6, lane = tid & 63;
  const int bm = blockIdx.x * 128, bn = blockIdx.y * BN;
  const int lda = 4 * K;
  const unsigned short* Ag = Zb + (size_t)h * K;
  const unsigned short* Bg = Wb + (size_t)h * N * K;
  const int lrow = lane >> 3;
  const int gseg = (lane & 7) ^ lrow;
  f32x4 acc[2][FN];
#pragma unroll
  for (int i = 0; i < 2; ++i)
#pragma unroll
    for (int j = 0; j < FN; ++j) acc[i][j] = (f32x4){0.f, 0.f, 0.f, 0.f};

  for (int k0 = 0; k0 < K; k0 += 64) {
    __syncthreads();
#pragma unroll
    for (int i = 0; i < AI; ++i) {
      int ch = w * AI + i;
      int row = ch * 8 + lrow;
      int gm = bm + row; gm = gm < M ? gm : M - 1;
      gload16(Ag + (size_t)gm * lda + k0 + gseg * 8, As + ch * 512);
    }
#pragma unroll
    for (int i = 0; i < BI; ++i) {
      int ch = w * BI + i;
      int row = ch * 8 + lrow;
      int gn = bn + row; gn = gn < N ? gn : N - 1;
      gload16(Bg + (size_t)gn * K + k0 + gseg * 8, Bs + ch * 512);
    }
    __syncthreads();
    const int ra = w * 32 + (lane & 15);
#pragma unroll
    for (int ks = 0; ks < 2; ++ks) {
      int cs = ((((ks << 2) + (lane >> 4)) ^ (lane & 7)) << 3);
      bf8_t a0 = *reinterpret_cast<const bf8_t*>(As + ra * 64 + cs);
      bf8_t a1 = *reinterpret_cast<const bf8_t*>(As + (ra + 16) * 64 + cs);
#pragma unroll
      for (int fn = 0; fn < FN; ++fn) {
        bf8_t bf = *reinterpret_cast<const bf8_t*>(Bs + (fn * 16 + (lane & 15)) * 64 + cs);
        acc[0][fn] = __builtin_amdgcn_mfma_f32_16x16x32_bf16(a0, bf, acc[0][fn], 0, 0, 0);
        acc[1][fn] = __builtin_amdgcn_mfma_f32_16x16x32_bf16(a1, bf, acc[1][fn], 0, 0, 0);
      }
    }
  }
  int ldo = 4 * N;
#pragma unroll
  for (int fm = 0; fm < 2; ++fm) {
#pragma unroll
    for (int fn = 0; fn < FN; ++fn) {
      int colb = bn + fn * 16 + (lane & 15);
      if (colb >= N) continue;
      float bv = bias[h * N + colb];
#pragma unroll
      for (int j = 0; j < 4; ++j) {
        int rowb = bm + w * 32 + fm * 16 + (lane >> 4) * 4 + j;
        if (rowb >= M) continue;
        float v = acc[fm][fn][j] + bv;
        if (ACT) v = v > 0.f ? v : (__expf(v) - 1.f);
        size_t off = (size_t)rowb * ldo + (size_t)h * N + colb;
        if (OUTBF) ((unsigned short*)outv)[off] = f2b(v);
        else ((float*)outv)[off] = v;
      }
    }
  }
}

// mean over 4 heads (C=47) + log_softmax; one wave per node
__global__ __launch_bounds__(256) void k_mean_lsm(const float* __restrict__ rst2,
                                                  float* __restrict__ out, int Nd) {
  int node = blockIdx.x * 4 + (threadIdx.x >> 6);
  int lane = threadIdx.x & 63;
  if (node >= Nd) return;
  const float* r = rst2 + (size_t)node * 188;
  float vv = 0.f;
  if (lane < 47)
    vv = 0.25f * (r[lane] + r[47 + lane] + r[94 + lane] + r[141 + lane]);
  float m = (lane < 47) ? vv : -INFINITY;
  for (int off = 32; off > 0; off >>= 1) m = fmaxf(m, __shfl_xor(m, off));
  float ex = (lane < 47) ? __expf(vv - m) : 0.f;
  float ss = ex;
  for (int off = 32; off > 0; off >>= 1) ss += __shfl_xor(ss, off);
  if (lane < 47) out[(size_t)node * 47 + lane] = vv - m - logf(ss);
}

extern "C" void kernel_launch(void* const* d_in, const int* in_sizes, int n_in,
                              void* d_out, int out_size, void* d_ws, size_t ws_size,
                              hipStream_t stream) {
  (void)in_sizes; (void)n_in; (void)out_size; (void)ws_size;
  const float* x = (const float*)d_in[0];
  const int* srcs[3] = {(const int*)d_in[1], (const int*)d_in[3], (const int*)d_in[5]};
  const int* dsts[3] = {(const int*)d_in[2], (const int*)d_in[4], (const int*)d_in[6]};
  const float* Wsrc[3] = {(const float*)d_in[7], (const float*)d_in[12], (const float*)d_in[17]};
  const float* Wdst[3] = {(const float*)d_in[8], (const float*)d_in[13], (const float*)d_in[18]};
  const float* al[3]   = {(const float*)d_in[9], (const float*)d_in[14], (const float*)d_in[19]};
  const float* ar[3]   = {(const float*)d_in[10], (const float*)d_in[15], (const float*)d_in[20]};
  const float* bb[3]   = {(const float*)d_in[11], (const float*)d_in[16], (const float*)d_in[21]};

  char* p = (char*)d_ws;
  auto alloc = [&](size_t bytes) -> void* {
    void* r = (void*)p;
    p += (bytes + 255) & ~(size_t)255;
    return r;
  };
  unsigned short* zbf = (unsigned short*)alloc((size_t)25000 * 1024 * 2);
  unsigned short* h1  = (unsigned short*)alloc((size_t)25000 * 512 * 2);
  unsigned short* h2  = (unsigned short*)alloc((size_t)6000 * 512 * 2);
  float* rst2   = (float*)alloc((size_t)1024 * 188 * 4);
  unsigned short* Wb0 = (unsigned short*)alloc((size_t)512 * 256 * 2);
  unsigned short* Wb1 = (unsigned short*)alloc((size_t)512 * 512 * 2);
  unsigned short* Wb2 = (unsigned short*)alloc((size_t)188 * 512 * 2);
  float* ell    = (float*)alloc((size_t)150000 * 4 * 4);
  float* err    = (float*)alloc((size_t)25000 * 4 * 4);
  int* cntAll   = (int*)alloc((size_t)NTOT * 4);
  int* Sarr     = (int*)alloc((size_t)(NTOT + 8) * 4);
  int* btot     = (int*)alloc((size_t)((NCH + 7) & ~7) * 4);
  int* r_all    = (int*)alloc((size_t)ETOT * 4);
  int* cvAll    = (int*)alloc((size_t)ETOT * 4);
  unsigned short* wlrb = (unsigned short*)alloc((size_t)16 * 264 * 2);
  float* wlr1   = (float*)alloc((size_t)8 * 512 * 4);
  float* wlr2   = (float*)alloc((size_t)8 * 512 * 4);

  hipMemsetAsync(cntAll, 0, (size_t)NTOT * 4, stream);
  k_prep_count<<<(ETOT + 255) / 256, 256, 0, stream>>>(
      dsts[0], dsts[1], dsts[2], cntAll, r_all,
      Wsrc[0], Wdst[0], al[0], ar[0], Wsrc[1], Wdst[1], al[1], ar[1],
      Wsrc[2], Wdst[2], al[2], ar[2], wlrb, wlr1, wlr2, Wb0, Wb1, Wb2);
  k_scanA<<<NCH, 128, 0, stream>>>(cntAll, Sarr, btot, NTOT);
  k_scanB<<<NCH, 256, 0, stream>>>(btot, Sarr, NTOT, ETOT);
  k_scatter_all<<<(ETOT + 255) / 256, 256, 0, stream>>>(
      srcs[0], dsts[0], srcs[1], dsts[1], srcs[2], dsts[2], Sarr, r_all, cvAll);

  const unsigned short* Hbf[3] = {nullptr, h1, h2};
  const unsigned short* Wbf[3] = {Wb0, Wb1, Wb2};
  const float* wlrs[3] = {nullptr, wlr1, wlr2};
  const int noff[3] = {0, ND0, ND0 + ND1};

  for (int l = 0; l < 3; ++l) {
    int Ns = L_NS[l], Nd = L_ND[l];
    if (l == 0) {
      // DIAGNOSTIC: 3x launches of each L0 heavy kernel (idempotent).
      for (int rep = 0; rep < 3; ++rep)
        k_dotc_mfma<<<(Ns + 127) / 128, 256, 0, stream>>>(x, wlrb, ell, err, Ns, Nd);
      for (int rep = 0; rep < 3; ++rep)
        k_gather4<256, true><<<(Nd + 3) / 4, 256, 0, stream>>>(
            x, ell, err, Sarr + noff[l], cvAll, zbf, Nd);
    } else {
      k_dot_bf<<<(Ns + 3) / 4, 256, 0, stream>>>(Hbf[l], wlrs[l], ell, err, Ns, Nd);
      k_gather4<512, false><<<(Nd + 3) / 4, 256, 0, stream>>>(
          Hbf[l], ell, err, Sarr + noff[l], cvAll, zbf, Nd);
    }
    dim3 g((Nd + 127) / 128, 1, 4);
    if (l == 0) {
      for (int rep = 0; rep < 3; ++rep)
        k_gemm_mfma<128, true, true><<<g, 256, 0, stream>>>(zbf, Wbf[l], bb[l], h1, Nd, 128, 256);
    } else if (l == 1) {
      k_gemm_mfma<128, true, true><<<g, 256, 0, stream>>>(zbf, Wbf[l], bb[l], h2, Nd, 128, 512);
    } else {
      k_gemm_mfma<64, false, false><<<g, 256, 0, stream>>>(zbf, Wbf[l], bb[l], rst2, Nd, 47, 512);
    }
  }
  k_mean_lsm<<<(1024 + 3) / 4, 256, 0, stream>>>(rst2, (float*)d_out, 1024);
}

// Round 14
// 253.797 us; speedup vs baseline: 2.1295x; 2.1295x over previous
//
#include <hip/hip_runtime.h>
#include <math.h>

// ---------------------------------------------------------------------------
// GAT 3-layer pipeline. bf16 features + MFMA GEMMs, fused CSR edge-softmax.
//   el = h @ wl.T, wl[h,:] = al[h,:] @ Wsrc_h   (no fs materialization)
//   agg = (softmax-weighted sum of raw feats) @ Wsrc_h.T  (aggregate first)
// L0 dot: MFMA. Gathers: barrier-free wave-per-node. CSR: parallel scan.
// L0 GEMM: B panel fully LDS-resident (1 barrier), direct-global A fragments.
// prep: wlr tables built with coalesced row reads (block-per-head).
// ---------------------------------------------------------------------------

#define E0 375000
#define E1 90000
#define E2 10240
#define ETOT (E0 + E1 + E2)
#define ND0 25000
#define ND1 6000
#define ND2 1024
#define NTOT (ND0 + ND1 + ND2)   /* 32024 */
#define NCH ((NTOT + 127) / 128) /* 251 */

static const int L_NS[3]   = {150000, 25000, 6000};
static const int L_ND[3]   = {ND0, ND1, ND2};

typedef short bf8_t __attribute__((ext_vector_type(8)));
typedef float f32x4 __attribute__((ext_vector_type(4)));

__device__ __forceinline__ float lrelu(float v) { return v >= 0.f ? v : 0.2f * v; }
__device__ __forceinline__ unsigned short f2b(float f) {
  unsigned u = __float_as_uint(f);
  unsigned r = u + 0x7fffu + ((u >> 16) & 1u);
  return (unsigned short)(r >> 16);
}
__device__ __forceinline__ float b2f(unsigned v) {  // low 16 bits
  return __uint_as_float(v << 16);
}
__device__ __forceinline__ unsigned bpack(float a, float b) {
  return (unsigned)f2b(a) | ((unsigned)f2b(b) << 16);
}

__device__ __forceinline__ void gload16(const unsigned short* g, unsigned short* l) {
  __builtin_amdgcn_global_load_lds(
      (const __attribute__((address_space(1))) unsigned int*)g,
      (__attribute__((address_space(3))) unsigned int*)l, 16, 0, 0);
}

// ---------------- prologue (one-shot, topology/weights only) ----------------

// edge counting (all blocks, gid-based) + coalesced wlr builds (blocks 0-24)
// + bf16 weight conversion (grid-stride).
__global__ void k_prep_count(
    const int* __restrict__ d0, const int* __restrict__ d1,
    const int* __restrict__ d2, int* __restrict__ cntAll, int* __restrict__ r,
    const float* __restrict__ Ws0, const float* __restrict__ Wd0,
    const float* __restrict__ al0, const float* __restrict__ ar0,
    const float* __restrict__ Ws1, const float* __restrict__ Wd1,
    const float* __restrict__ al1, const float* __restrict__ ar1,
    const float* __restrict__ Ws2, const float* __restrict__ Wd2,
    const float* __restrict__ al2, const float* __restrict__ ar2,
    unsigned short* __restrict__ wlrb, float* __restrict__ wlr1,
    float* __restrict__ wlr2,
    unsigned short* __restrict__ B0, unsigned short* __restrict__ B1,
    unsigned short* __restrict__ B2) {
  const int b = blockIdx.x, t = threadIdx.x;
  int gid = b * 256 + t;
  // edge counts (ordinal out)
  if (gid < ETOT) {
    int goff, dv;
    if (gid < E0) { goff = 0; dv = d0[gid]; }
    else if (gid < E0 + E1) { goff = ND0; dv = d1[gid - E0]; }
    else { goff = ND0 + ND1; dv = d2[gid - E0 - E1]; }
    r[gid] = atomicAdd(&cntAll[goff + dv], 1);
  }
  // coalesced wlr-table builds
  if (b < 8) {
    // wlrb row h=b: k = t (256 cols), d-loop over 128 coalesced W rows
    int h = b, hh = h & 3;
    const float* W = (h < 4) ? Ws0 : Wd0;
    const float* a = (h < 4) ? al0 : ar0;
    float acc = 0.f;
    for (int d = 0; d < 128; ++d)
      acc = fmaf(a[hh * 128 + d], W[(size_t)(hh * 128 + d) * 256 + t], acc);
    wlrb[h * 264 + t] = f2b(acc);
  } else if (b == 8) {
    for (int i = t; i < 8 * 264; i += 256) wlrb[8 * 264 + i] = 0;  // zero rows 8-15
  } else if (b < 17) {
    // wlr1: idx 0..7 -> (which = idx>>2, h = idx&3); k spans 512 in 2 chunks
    int idx = b - 9, which = idx >> 2, h = idx & 3;
    const float* W = which ? Wd1 : Ws1;
    const float* a = which ? ar1 : al1;
#pragma unroll
    for (int kc = 0; kc < 2; ++kc) {
      int k = kc * 256 + t;
      float acc = 0.f;
      for (int d = 0; d < 128; ++d)
        acc = fmaf(a[h * 128 + d], W[(size_t)(h * 128 + d) * 512 + k], acc);
      wlr1[which * 2048 + h * 512 + k] = acc;
    }
  } else if (b < 25) {
    int idx = b - 17, which = idx >> 2, h = idx & 3;
    const float* W = which ? Wd2 : Ws2;
    const float* a = which ? ar2 : al2;
#pragma unroll
    for (int kc = 0; kc < 2; ++kc) {
      int k = kc * 256 + t;
      float acc = 0.f;
      for (int d = 0; d < 47; ++d)
        acc = fmaf(a[h * 47 + d], W[(size_t)(h * 47 + d) * 512 + k], acc);
      wlr2[which * 2048 + h * 512 + k] = acc;
    }
  }
  // bf16 weight conversion
  const int n0 = 512 * 256, n1 = 512 * 512, n2 = 188 * 512;
  for (int i = gid; i < n0 + n1 + n2; i += gridDim.x * 256) {
    if (i < n0) B0[i] = f2b(Ws0[i]);
    else if (i < n0 + n1) B1[i - n0] = f2b(Ws1[i - n0]);
    else B2[i - n0 - n1] = f2b(Ws2[i - n0 - n1]);
  }
}

__global__ __launch_bounds__(128) void k_scanA(const int* __restrict__ cnt,
                                               int* __restrict__ S,
                                               int* __restrict__ btot, int n) {
  __shared__ int wt[2];
  int c = blockIdx.x, t = threadIdx.x, lane = t & 63, w = t >> 6;
  int g = c * 128 + t;
  int v = (g < n) ? cnt[g] : 0;
  int incl = v;
  for (int off = 1; off < 64; off <<= 1) {
    int u = __shfl_up(incl, off);
    if (lane >= off) incl += u;
  }
  if (lane == 63) wt[w] = incl;
  __syncthreads();
  int base = (w == 1) ? wt[0] : 0;
  if (g < n) S[g] = incl - v + base;
  if (t == 127) btot[c] = wt[0] + wt[1];
}

__global__ __launch_bounds__(256) void k_scanB(const int* __restrict__ btot,
                                               int* __restrict__ S, int n, int etot) {
  __shared__ int tv[256];
  int c = blockIdx.x, t = threadIdx.x;
  int own = (t < NCH) ? btot[t] : 0;
  tv[t] = own;
  __syncthreads();
  for (int off = 1; off < 256; off <<= 1) {
    int u = (t >= off) ? tv[t - off] : 0;
    __syncthreads();
    tv[t] += u;
    __syncthreads();
  }
  int base = tv[c] - btot[c];
  int g = c * 128 + (t & 127);
  if (t < 128 && g < n) S[g] += base;
  if (c == 0 && t == 255) S[n] = etot;
}

__global__ void k_scatter_all(
    const int* __restrict__ s0, const int* __restrict__ d0,
    const int* __restrict__ s1, const int* __restrict__ d1,
    const int* __restrict__ s2, const int* __restrict__ d2,
    const int* __restrict__ S, const int* __restrict__ r,
    int* __restrict__ cvAll) {
  int g = blockIdx.x * 256 + threadIdx.x;
  if (g >= ETOT) return;
  int goff, dv, sv;
  if (g < E0) { goff = 0; dv = d0[g]; sv = s0[g]; }
  else if (g < E0 + E1) { int e = g - E0; goff = ND0; dv = d1[e]; sv = s1[e]; }
  else { int e = g - E0 - E1; goff = ND0 + ND1; dv = d2[e]; sv = s2[e]; }
  cvAll[S[goff + dv] + r[g]] = sv;
}

// ---------------- per-layer feature kernels ----------------

__global__ __launch_bounds__(256) void k_dotc_mfma(
    const float* __restrict__ x, const unsigned short* __restrict__ wlrb,
    float* __restrict__ ell, float* __restrict__ err, int Ns, int Nd) {
  __shared__ unsigned short As[128 * 72];
  __shared__ unsigned short Bs[16 * 264];
  const int tid = threadIdx.x;
  const int w = tid >> 6, lane = tid & 63;
  const int bm = blockIdx.x * 128;
  const int rowg = tid >> 4;
  const int seg  = tid & 15;
  for (int i = tid; i < 16 * 264; i += 256) Bs[i] = wlrb[i];
  f32x4 acc[2] = {};
  for (int k0 = 0; k0 < 256; k0 += 64) {
    __syncthreads();
#pragma unroll
    for (int i = 0; i < 8; ++i) {
      int row = rowg + i * 16;
      int gm = bm + row;
      int gmc = gm < Ns ? gm : Ns - 1;
      float4 a = *reinterpret_cast<const float4*>(x + (size_t)gmc * 256 + k0 + seg * 4);
      ushort4 ub;
      ub.x = f2b(a.x); ub.y = f2b(a.y); ub.z = f2b(a.z); ub.w = f2b(a.w);
      *reinterpret_cast<ushort4*>(&As[row * 72 + seg * 4]) = ub;
    }
    __syncthreads();
    const int ra = w * 32 + (lane & 15);
    const int kf = (lane >> 4) * 8;
#pragma unroll
    for (int ks = 0; ks < 2; ++ks) {
      bf8_t b0 = *reinterpret_cast<const bf8_t*>(&Bs[(lane & 15) * 264 + k0 + ks * 32 + kf]);
      bf8_t a0 = *reinterpret_cast<const bf8_t*>(&As[ra * 72 + ks * 32 + kf]);
      bf8_t a1 = *reinterpret_cast<const bf8_t*>(&As[(ra + 16) * 72 + ks * 32 + kf]);
      acc[0] = __builtin_amdgcn_mfma_f32_16x16x32_bf16(a0, b0, acc[0], 0, 0, 0);
      acc[1] = __builtin_amdgcn_mfma_f32_16x16x32_bf16(a1, b0, acc[1], 0, 0, 0);
    }
  }
  int col = lane & 15;
#pragma unroll
  for (int fm = 0; fm < 2; ++fm) {
#pragma unroll
    for (int j = 0; j < 4; ++j) {
      int node = bm + w * 32 + fm * 16 + (lane >> 4) * 4 + j;
      if (node >= Ns) continue;
      float v = acc[fm][j];
      if (col < 4) ell[(size_t)node * 4 + col] = v;
      else if (col < 8 && node < Nd) err[(size_t)node * 4 + (col - 4)] = v;
    }
  }
}

__device__ __forceinline__ void reduce8_store(float v[8], int lane, int node, int Nd,
                                              float* __restrict__ ell,
                                              float* __restrict__ err) {
#pragma unroll
  for (int h = 0; h < 8; ++h) {
    v[h] += __shfl_xor(v[h], 8);
    v[h] += __shfl_xor(v[h], 16);
    v[h] += __shfl_xor(v[h], 32);
  }
  int sel = lane >> 3;
  float t01 = (sel & 1) ? v[1] : v[0];
  float t23 = (sel & 1) ? v[3] : v[2];
  float t45 = (sel & 1) ? v[5] : v[4];
  float t67 = (sel & 1) ? v[7] : v[6];
  float t03 = (sel & 2) ? t23 : t01;
  float t47 = (sel & 2) ? t67 : t45;
  float s   = (sel & 4) ? t47 : t03;
  s += __shfl_xor(s, 1);
  s += __shfl_xor(s, 2);
  s += __shfl_xor(s, 4);
  if ((lane & 7) == 0) {
    if (sel < 4) ell[(size_t)node * 4 + sel] = s;
    else if (node < Nd) err[(size_t)node * 4 + (sel - 4)] = s;
  }
}

__global__ __launch_bounds__(256) void k_dot_bf(
    const unsigned short* __restrict__ Hs, const float* __restrict__ wlr,
    float* __restrict__ ell, float* __restrict__ err, int Ns, int Nd) {
  int node = blockIdx.x * 4 + (threadIdx.x >> 6);
  int lane = threadIdx.x & 63;
  if (node >= Ns) return;
  uint4 raw = *reinterpret_cast<const uint4*>(Hs + (size_t)node * 512 + lane * 8);
  float xv[8];
  xv[0] = b2f(raw.x & 0xffffu); xv[1] = b2f(raw.x >> 16);
  xv[2] = b2f(raw.y & 0xffffu); xv[3] = b2f(raw.y >> 16);
  xv[4] = b2f(raw.z & 0xffffu); xv[5] = b2f(raw.z >> 16);
  xv[6] = b2f(raw.w & 0xffffu); xv[7] = b2f(raw.w >> 16);
  bool nR = node < Nd;
  float v[8];
#pragma unroll
  for (int h = 0; h < 4; ++h) {
    const float* wp = wlr + h * 512 + lane * 8;
    float4 w0 = *reinterpret_cast<const float4*>(wp);
    float4 w1 = *reinterpret_cast<const float4*>(wp + 4);
    v[h] = xv[0]*w0.x + xv[1]*w0.y + xv[2]*w0.z + xv[3]*w0.w +
           xv[4]*w1.x + xv[5]*w1.y + xv[6]*w1.z + xv[7]*w1.w;
    v[4 + h] = 0.f;
    if (nR) {
      const float* wq = wlr + 2048 + h * 512 + lane * 8;
      float4 u0 = *reinterpret_cast<const float4*>(wq);
      float4 u1 = *reinterpret_cast<const float4*>(wq + 4);
      v[4 + h] = xv[0]*u0.x + xv[1]*u0.y + xv[2]*u0.z + xv[3]*u0.w +
                 xv[4]*u1.x + xv[5]*u1.y + xv[6]*u1.z + xv[7]*u1.w;
    }
  }
  reduce8_store(v, lane, node, Nd, ell, err);
}

// Unified gather: one WAVE per dst node, 4 nodes per block, barrier-free.
template <int FIN, bool F32>
__global__ __launch_bounds__(256) void k_gather4(
    const void* __restrict__ Hv, const float* __restrict__ ell,
    const float* __restrict__ err, const int* __restrict__ rowptr,
    const int* __restrict__ colv, unsigned short* __restrict__ Z, int Nd) {
  constexpr int CPL = F32 ? 4 : 8;
  constexpr int CAP = 256;
  __shared__ float4 esm_all[4][CAP];
  __shared__ int csm_all[4][CAP];
  int w = threadIdx.x >> 6, lane = threadIdx.x & 63;
  int n = blockIdx.x * 4 + w;
  if (n >= Nd) return;
  float4* esm = esm_all[w];
  int* csm = csm_all[w];
  int beg = rowptr[n], cnt = rowptr[n + 1] - beg;
  float4 er4 = *reinterpret_cast<const float4*>(err + (size_t)n * 4);
  float m0 = -INFINITY, m1 = -INFINITY, m2 = -INFINITY, m3 = -INFINITY;
  for (int i = lane; i < cnt; i += 64) {
    int c = colv[beg + i];
    float4 el4 = *reinterpret_cast<const float4*>(ell + (size_t)c * 4);
    float4 e4;
    e4.x = lrelu(el4.x + er4.x); e4.y = lrelu(el4.y + er4.y);
    e4.z = lrelu(el4.z + er4.z); e4.w = lrelu(el4.w + er4.w);
    if (i < CAP) { csm[i] = c; esm[i] = e4; }
    m0 = fmaxf(m0, e4.x); m1 = fmaxf(m1, e4.y);
    m2 = fmaxf(m2, e4.z); m3 = fmaxf(m3, e4.w);
  }
  for (int off = 32; off > 0; off >>= 1) {
    m0 = fmaxf(m0, __shfl_xor(m0, off));
    m1 = fmaxf(m1, __shfl_xor(m1, off));
    m2 = fmaxf(m2, __shfl_xor(m2, off));
    m3 = fmaxf(m3, __shfl_xor(m3, off));
  }
  __builtin_amdgcn_sched_barrier(0);
  float s0 = 0.f, s1 = 0.f, s2 = 0.f, s3 = 0.f;
  float acc[4][CPL] = {};

  auto loadrow = [&](int c, float xv[CPL]) {
    if constexpr (F32) {
      float4 a = *reinterpret_cast<const float4*>(
          (const float*)Hv + (size_t)c * FIN + lane * 4);
      xv[0] = a.x; xv[1] = a.y; xv[2] = a.z; xv[3] = a.w;
    } else {
      uint4 raw = *reinterpret_cast<const uint4*>(
          (const unsigned short*)Hv + (size_t)c * FIN + lane * 8);
      xv[0] = b2f(raw.x & 0xffffu); xv[1] = b2f(raw.x >> 16);
      xv[2] = b2f(raw.y & 0xffffu); xv[3] = b2f(raw.y >> 16);
      xv[4] = b2f(raw.z & 0xffffu); xv[5] = b2f(raw.z >> 16);
      xv[6] = b2f(raw.w & 0xffffu); xv[7] = b2f(raw.w >> 16);
    }
  };
  auto accum = [&](float4 w4, const float xv[CPL]) {
    s0 += w4.x; s1 += w4.y; s2 += w4.z; s3 += w4.w;
#pragma unroll
    for (int c2 = 0; c2 < CPL; ++c2) {
      acc[0][c2] = fmaf(w4.x, xv[c2], acc[0][c2]);
      acc[1][c2] = fmaf(w4.y, xv[c2], acc[1][c2]);
      acc[2][c2] = fmaf(w4.z, xv[c2], acc[2][c2]);
      acc[3][c2] = fmaf(w4.w, xv[c2], acc[3][c2]);
    }
  };

  if (cnt <= CAP) {
    for (int i = lane; i < cnt; i += 64) {
      float4 e = esm[i];
      esm[i] = make_float4(__expf(e.x - m0), __expf(e.y - m1),
                           __expf(e.z - m2), __expf(e.w - m3));
    }
    __builtin_amdgcn_sched_barrier(0);
    int j = 0;
    for (; j + 2 <= cnt; j += 2) {
      int c0 = csm[j], c1 = csm[j + 1];
      float4 wa = esm[j], wb = esm[j + 1];
      float xa[CPL], xb[CPL];
      loadrow(c0, xa);
      loadrow(c1, xb);
      accum(wa, xa);
      accum(wb, xb);
    }
    if (j < cnt) {
      float xa[CPL];
      loadrow(csm[j], xa);
      accum(esm[j], xa);
    }
  } else {
    for (int j = 0; j < cnt; ++j) {
      int c = colv[beg + j];
      float4 el4 = *reinterpret_cast<const float4*>(ell + (size_t)c * 4);
      float4 w4;
      w4.x = __expf(lrelu(el4.x + er4.x) - m0);
      w4.y = __expf(lrelu(el4.y + er4.y) - m1);
      w4.z = __expf(lrelu(el4.z + er4.z) - m2);
      w4.w = __expf(lrelu(el4.w + er4.w) - m3);
      float xa[CPL];
      loadrow(c, xa);
      accum(w4, xa);
    }
  }
  float inv[4];
  inv[0] = 1.f / fmaxf(s0, 1e-9f); inv[1] = 1.f / fmaxf(s1, 1e-9f);
  inv[2] = 1.f / fmaxf(s2, 1e-9f); inv[3] = 1.f / fmaxf(s3, 1e-9f);
#pragma unroll
  for (int h = 0; h < 4; ++h) {
    if constexpr (F32) {
      ushort4 o;
      o.x = f2b(acc[h][0] * inv[h]); o.y = f2b(acc[h][1] * inv[h]);
      o.z = f2b(acc[h][2] * inv[h]); o.w = f2b(acc[h][3] * inv[h]);
      *reinterpret_cast<ushort4*>(Z + (size_t)n * 4 * FIN + h * FIN + lane * 4) = o;
    } else {
      uint4 o;
      o.x = bpack(acc[h][0] * inv[h], acc[h][1] * inv[h]);
      o.y = bpack(acc[h][2] * inv[h], acc[h][3] * inv[h]);
      o.z = bpack(acc[h][4] * inv[h], acc[h][5] * inv[h]);
      o.w = bpack(acc[h][6] * inv[h], acc[h][7] * inv[h]);
      *reinterpret_cast<uint4*>(Z + (size_t)n * 4 * FIN + h * FIN + lane * 8) = o;
    }
  }
}

// L0 GEMM: K=256, N=128. Full B panel LDS-resident (64KB, ONE barrier);
// A fragments loaded directly from global -> zero k-loop barriers.
__global__ __launch_bounds__(256) void k_gemm_l0(
    const unsigned short* __restrict__ Zb, const unsigned short* __restrict__ Wb,
    const float* __restrict__ bias, unsigned short* __restrict__ out, int M) {
  __shared__ unsigned short Bs[4 * 128 * 64];  // 4 kb x [128 rows][64 cols], swizzled
  const int tid = threadIdx.x;
  const int w = tid >> 6, lane = tid & 63;
  const int h = blockIdx.z;
  const int bm = blockIdx.x * 128;
  const unsigned short* Ag = Zb + (size_t)h * 256;        // lda = 1024
  const unsigned short* Bg = Wb + (size_t)h * 128 * 256;  // [128][256]
  const int lrow = lane >> 3;
  const int gseg = (lane & 7) ^ lrow;
  // stage whole B panel (64 chunks of 8 rows x 64 cols; 16 per wave)
#pragma unroll
  for (int i = 0; i < 16; ++i) {
    int cidx = w * 16 + i;
    int kb = cidx >> 4, ch = cidx & 15;
    int row = ch * 8 + lrow;
    gload16(Bg + (size_t)row * 256 + kb * 64 + gseg * 8, Bs + kb * 8192 + ch * 512);
  }
  __syncthreads();  // single barrier: B resident for the whole kernel

  f32x4 acc[2][8];
#pragma unroll
  for (int i = 0; i < 2; ++i)
#pragma unroll
    for (int j = 0; j < 8; ++j) acc[i][j] = (f32x4){0.f, 0.f, 0.f, 0.f};

  const int colsel = lane >> 4;  // 0..3
  int rowA = bm + w * 32 + (lane & 15);
  int gm0 = rowA < M ? rowA : M - 1;
  int gm1 = (rowA + 16) < M ? (rowA + 16) : M - 1;
#pragma unroll
  for (int step = 0; step < 8; ++step) {
    int kb = step >> 1, ks = step & 1;
    int kcol = kb * 64 + ks * 32 + colsel * 8;
    bf8_t a0 = *reinterpret_cast<const bf8_t*>(Ag + (size_t)gm0 * 1024 + kcol);
    bf8_t a1 = *reinterpret_cast<const bf8_t*>(Ag + (size_t)gm1 * 1024 + kcol);
    int cs = ((((ks << 2) + colsel) ^ (lane & 7)) << 3);
#pragma unroll
    for (int fn = 0; fn < 8; ++fn) {
      bf8_t bf = *reinterpret_cast<const bf8_t*>(
          Bs + kb * 8192 + (fn * 16 + (lane & 15)) * 64 + cs);
      acc[0][fn] = __builtin_amdgcn_mfma_f32_16x16x32_bf16(a0, bf, acc[0][fn], 0, 0, 0);
      acc[1][fn] = __builtin_amdgcn_mfma_f32_16x16x32_bf16(a1, bf, acc[1][fn], 0, 0, 0);
    }
  }
#pragma unroll
  for (int fm = 0; fm < 2; ++fm) {
#pragma unroll
    for (int fn = 0; fn < 8; ++fn) {
      int colb = fn * 16 + (lane & 15);
      float bv = bias[h * 128 + colb];
#pragma unroll
      for (int j = 0; j < 4; ++j) {
        int rowb = bm + w * 32 + fm * 16 + (lane >> 4) * 4 + j;
        if (rowb >= M) continue;
        float v = acc[fm][fn][j] + bv;
        v = v > 0.f ? v : (__expf(v) - 1.f);
        out[(size_t)rowb * 512 + h * 128 + colb] = f2b(v);
      }
    }
  }
}

// bf16 MFMA GEMM (proven; used for L1/L2)
template <int BN, bool ACT, bool OUTBF>
__global__ __launch_bounds__(256) void k_gemm_mfma(
    const unsigned short* __restrict__ Zb, const unsigned short* __restrict__ Wb,
    const float* __restrict__ bias, void* __restrict__ outv,
    int M, int N, int K) {
  constexpr int FN = BN / 16;
  constexpr int AI = 4;
  constexpr int BI = BN / 32;
  int h = blockIdx.z;
  __shared__ unsigned short As[128 * 64];
  __shared__ unsigned short Bs[BN * 64];
  const int tid = threadIdx.x;
  const int w = tid >> 6, lane = tid & 63;
  const int bm = blockIdx.x * 128, bn = blockIdx.y * BN;
  const int lda = 4 * K;
  const unsigned short* Ag = Zb + (size_t)h * K;
  const unsigned short* Bg = Wb + (size_t)h * N * K;
  const int lrow = lane >> 3;
  const int gseg = (lane & 7) ^ lrow;
  f32x4 acc[2][FN];
#pragma unroll
  for (int i = 0; i < 2; ++i)
#pragma unroll
    for (int j = 0; j < FN; ++j) acc[i][j] = (f32x4){0.f, 0.f, 0.f, 0.f};

  for (int k0 = 0; k0 < K; k0 += 64) {
    __syncthreads();
#pragma unroll
    for (int i = 0; i < AI; ++i) {
      int ch = w * AI + i;
      int row = ch * 8 + lrow;
      int gm = bm + row; gm = gm < M ? gm : M - 1;
      gload16(Ag + (size_t)gm * lda + k0 + gseg * 8, As + ch * 512);
    }
#pragma unroll
    for (int i = 0; i < BI; ++i) {
      int ch = w * BI + i;
      int row = ch * 8 + lrow;
      int gn = bn + row; gn = gn < N ? gn : N - 1;
      gload16(Bg + (size_t)gn * K + k0 + gseg * 8, Bs + ch * 512);
    }
    __syncthreads();
    const int ra = w * 32 + (lane & 15);
#pragma unroll
    for (int ks = 0; ks < 2; ++ks) {
      int cs = ((((ks << 2) + (lane >> 4)) ^ (lane & 7)) << 3);
      bf8_t a0 = *reinterpret_cast<const bf8_t*>(As + ra * 64 + cs);
      bf8_t a1 = *reinterpret_cast<const bf8_t*>(As + (ra + 16) * 64 + cs);
#pragma unroll
      for (int fn = 0; fn < FN; ++fn) {
        bf8_t bf = *reinterpret_cast<const bf8_t*>(Bs + (fn * 16 + (lane & 15)) * 64 + cs);
        acc[0][fn] = __builtin_amdgcn_mfma_f32_16x16x32_bf16(a0, bf, acc[0][fn], 0, 0, 0);
        acc[1][fn] = __builtin_amdgcn_mfma_f32_16x16x32_bf16(a1, bf, acc[1][fn], 0, 0, 0);
      }
    }
  }
  int ldo = 4 * N;
#pragma unroll
  for (int fm = 0; fm < 2; ++fm) {
#pragma unroll
    for (int fn = 0; fn < FN; ++fn) {
      int colb = bn + fn * 16 + (lane & 15);
      if (colb >= N) continue;
      float bv = bias[h * N + colb];
#pragma unroll
      for (int j = 0; j < 4; ++j) {
        int rowb = bm + w * 32 + fm * 16 + (lane >> 4) * 4 + j;
        if (rowb >= M) continue;
        float v = acc[fm][fn][j] + bv;
        if (ACT) v = v > 0.f ? v : (__expf(v) - 1.f);
        size_t off = (size_t)rowb * ldo + (size_t)h * N + colb;
        if (OUTBF) ((unsigned short*)outv)[off] = f2b(v);
        else ((float*)outv)[off] = v;
      }
    }
  }
}

// mean over 4 heads (C=47) + log_softmax; one wave per node
__global__ __launch_bounds__(256) void k_mean_lsm(const float* __restrict__ rst2,
                                                  float* __restrict__ out, int Nd) {
  int node = blockIdx.x * 4 + (threadIdx.x >> 6);
  int lane = threadIdx.x & 63;
  if (node >= Nd) return;
  const float* r = rst2 + (size_t)node * 188;
  float vv = 0.f;
  if (lane < 47)
    vv = 0.25f * (r[lane] + r[47 + lane] + r[94 + lane] + r[141 + lane]);
  float m = (lane < 47) ? vv : -INFINITY;
  for (int off = 32; off > 0; off >>= 1) m = fmaxf(m, __shfl_xor(m, off));
  float ex = (lane < 47) ? __expf(vv - m) : 0.f;
  float ss = ex;
  for (int off = 32; off > 0; off >>= 1) ss += __shfl_xor(ss, off);
  if (lane < 47) out[(size_t)node * 47 + lane] = vv - m - logf(ss);
}

extern "C" void kernel_launch(void* const* d_in, const int* in_sizes, int n_in,
                              void* d_out, int out_size, void* d_ws, size_t ws_size,
                              hipStream_t stream) {
  (void)in_sizes; (void)n_in; (void)out_size; (void)ws_size;
  const float* x = (const float*)d_in[0];
  const int* srcs[3] = {(const int*)d_in[1], (const int*)d_in[3], (const int*)d_in[5]};
  const int* dsts[3] = {(const int*)d_in[2], (const int*)d_in[4], (const int*)d_in[6]};
  const float* Wsrc[3] = {(const float*)d_in[7], (const float*)d_in[12], (const float*)d_in[17]};
  const float* Wdst[3] = {(const float*)d_in[8], (const float*)d_in[13], (const float*)d_in[18]};
  const float* al[3]   = {(const float*)d_in[9], (const float*)d_in[14], (const float*)d_in[19]};
  const float* ar[3]   = {(const float*)d_in[10], (const float*)d_in[15], (const float*)d_in[20]};
  const float* bb[3]   = {(const float*)d_in[11], (const float*)d_in[16], (const float*)d_in[21]};

  char* p = (char*)d_ws;
  auto alloc = [&](size_t bytes) -> void* {
    void* r = (void*)p;
    p += (bytes + 255) & ~(size_t)255;
    return r;
  };
  unsigned short* zbf = (unsigned short*)alloc((size_t)25000 * 1024 * 2);
  unsigned short* h1  = (unsigned short*)alloc((size_t)25000 * 512 * 2);
  unsigned short* h2  = (unsigned short*)alloc((size_t)6000 * 512 * 2);
  float* rst2   = (float*)alloc((size_t)1024 * 188 * 4);
  unsigned short* Wb0 = (unsigned short*)alloc((size_t)512 * 256 * 2);
  unsigned short* Wb1 = (unsigned short*)alloc((size_t)512 * 512 * 2);
  unsigned short* Wb2 = (unsigned short*)alloc((size_t)188 * 512 * 2);
  float* ell    = (float*)alloc((size_t)150000 * 4 * 4);
  float* err    = (float*)alloc((size_t)25000 * 4 * 4);
  int* cntAll   = (int*)alloc((size_t)NTOT * 4);
  int* Sarr     = (int*)alloc((size_t)(NTOT + 8) * 4);
  int* btot     = (int*)alloc((size_t)((NCH + 7) & ~7) * 4);
  int* r_all    = (int*)alloc((size_t)ETOT * 4);
  int* cvAll    = (int*)alloc((size_t)ETOT * 4);
  unsigned short* wlrb = (unsigned short*)alloc((size_t)16 * 264 * 2);
  float* wlr1   = (float*)alloc((size_t)8 * 512 * 4);
  float* wlr2   = (float*)alloc((size_t)8 * 512 * 4);

  hipMemsetAsync(cntAll, 0, (size_t)NTOT * 4, stream);
  k_prep_count<<<(ETOT + 255) / 256, 256, 0, stream>>>(
      dsts[0], dsts[1], dsts[2], cntAll, r_all,
      Wsrc[0], Wdst[0], al[0], ar[0], Wsrc[1], Wdst[1], al[1], ar[1],
      Wsrc[2], Wdst[2], al[2], ar[2], wlrb, wlr1, wlr2, Wb0, Wb1, Wb2);
  k_scanA<<<NCH, 128, 0, stream>>>(cntAll, Sarr, btot, NTOT);
  k_scanB<<<NCH, 256, 0, stream>>>(btot, Sarr, NTOT, ETOT);
  k_scatter_all<<<(ETOT + 255) / 256, 256, 0, stream>>>(
      srcs[0], dsts[0], srcs[1], dsts[1], srcs[2], dsts[2], Sarr, r_all, cvAll);

  const unsigned short* Hbf[3] = {nullptr, h1, h2};
  const unsigned short* Wbf[3] = {Wb0, Wb1, Wb2};
  const float* wlrs[3] = {nullptr, wlr1, wlr2};
  const int noff[3] = {0, ND0, ND0 + ND1};

  for (int l = 0; l < 3; ++l) {
    int Ns = L_NS[l], Nd = L_ND[l];
    if (l == 0) {
      k_dotc_mfma<<<(Ns + 127) / 128, 256, 0, stream>>>(x, wlrb, ell, err, Ns, Nd);
      k_gather4<256, true><<<(Nd + 3) / 4, 256, 0, stream>>>(
          x, ell, err, Sarr + noff[l], cvAll, zbf, Nd);
    } else {
      k_dot_bf<<<(Ns + 3) / 4, 256, 0, stream>>>(Hbf[l], wlrs[l], ell, err, Ns, Nd);
      k_gather4<512, false><<<(Nd + 3) / 4, 256, 0, stream>>>(
          Hbf[l], ell, err, Sarr + noff[l], cvAll, zbf, Nd);
    }
    if (l == 0) {
      dim3 g((Nd + 127) / 128, 1, 4);
      k_gemm_l0<<<g, 256, 0, stream>>>(zbf, Wbf[l], bb[l], h1, Nd);
    } else if (l == 1) {
      dim3 g((Nd + 127) / 128, 1, 4);
      k_gemm_mfma<128, true, true><<<g, 256, 0, stream>>>(zbf, Wbf[l], bb[l], h2, Nd, 128, 512);
    } else {
      dim3 g((Nd + 127) / 128, 1, 4);
      k_gemm_mfma<64, false, false><<<g, 256, 0, stream>>>(zbf, Wbf[l], bb[l], rst2, Nd, 47, 512);
    }
  }
  k_mean_lsm<<<(1024 + 3) / 4, 256, 0, stream>>>(rst2, (float*)d_out, 1024);
}

// Round 15
// 251.934 us; speedup vs baseline: 2.1453x; 1.0074x over previous
//
#include <hip/hip_runtime.h>
#include <math.h>

// ---------------------------------------------------------------------------
// GAT 3-layer pipeline. bf16 features + MFMA GEMMs, fused CSR edge-softmax.
//   el = h @ wl.T, wl[h,:] = al[h,:] @ Wsrc_h   (no fs materialization)
//   agg = (softmax-weighted sum of raw feats) @ Wsrc_h.T  (aggregate first)
// L0 dot: MFMA, direct-global A (barrier-free; 1 barrier for B table).
// Gathers: barrier-free wave-per-node. CSR: parallel scan.
// L0 GEMM: B panel LDS-resident (1 barrier), direct-global A.
// L1 GEMM: split-K B-resident (3 barriers), direct-global A.
// ---------------------------------------------------------------------------

#define E0 375000
#define E1 90000
#define E2 10240
#define ETOT (E0 + E1 + E2)
#define ND0 25000
#define ND1 6000
#define ND2 1024
#define NTOT (ND0 + ND1 + ND2)   /* 32024 */
#define NCH ((NTOT + 127) / 128) /* 251 */

static const int L_NS[3]   = {150000, 25000, 6000};
static const int L_ND[3]   = {ND0, ND1, ND2};

typedef short bf8_t __attribute__((ext_vector_type(8)));
typedef float f32x4 __attribute__((ext_vector_type(4)));

__device__ __forceinline__ float lrelu(float v) { return v >= 0.f ? v : 0.2f * v; }
__device__ __forceinline__ unsigned short f2b(float f) {
  unsigned u = __float_as_uint(f);
  unsigned r = u + 0x7fffu + ((u >> 16) & 1u);
  return (unsigned short)(r >> 16);
}
__device__ __forceinline__ float b2f(unsigned v) {  // low 16 bits
  return __uint_as_float(v << 16);
}
__device__ __forceinline__ unsigned bpack(float a, float b) {
  return (unsigned)f2b(a) | ((unsigned)f2b(b) << 16);
}

__device__ __forceinline__ void gload16(const unsigned short* g, unsigned short* l) {
  __builtin_amdgcn_global_load_lds(
      (const __attribute__((address_space(1))) unsigned int*)g,
      (__attribute__((address_space(3))) unsigned int*)l, 16, 0, 0);
}

// ---------------- prologue (one-shot, topology/weights only) ----------------

__global__ void k_prep_count(
    const int* __restrict__ d0, const int* __restrict__ d1,
    const int* __restrict__ d2, int* __restrict__ cntAll, int* __restrict__ r,
    const float* __restrict__ Ws0, const float* __restrict__ Wd0,
    const float* __restrict__ al0, const float* __restrict__ ar0,
    const float* __restrict__ Ws1, const float* __restrict__ Wd1,
    const float* __restrict__ al1, const float* __restrict__ ar1,
    const float* __restrict__ Ws2, const float* __restrict__ Wd2,
    const float* __restrict__ al2, const float* __restrict__ ar2,
    unsigned short* __restrict__ wlrb, float* __restrict__ wlr1,
    float* __restrict__ wlr2,
    unsigned short* __restrict__ B0, unsigned short* __restrict__ B1,
    unsigned short* __restrict__ B2) {
  const int b = blockIdx.x, t = threadIdx.x;
  int gid = b * 256 + t;
  if (gid < ETOT) {
    int goff, dv;
    if (gid < E0) { goff = 0; dv = d0[gid]; }
    else if (gid < E0 + E1) { goff = ND0; dv = d1[gid - E0]; }
    else { goff = ND0 + ND1; dv = d2[gid - E0 - E1]; }
    r[gid] = atomicAdd(&cntAll[goff + dv], 1);
  }
  // coalesced wlr-table builds (blocks 0-24)
  if (b < 8) {
    int h = b, hh = h & 3;
    const float* W = (h < 4) ? Ws0 : Wd0;
    const float* a = (h < 4) ? al0 : ar0;
    float acc = 0.f;
    for (int d = 0; d < 128; ++d)
      acc = fmaf(a[hh * 128 + d], W[(size_t)(hh * 128 + d) * 256 + t], acc);
    wlrb[h * 264 + t] = f2b(acc);
  } else if (b == 8) {
    for (int i = t; i < 8 * 264; i += 256) wlrb[8 * 264 + i] = 0;
  } else if (b < 17) {
    int idx = b - 9, which = idx >> 2, h = idx & 3;
    const float* W = which ? Wd1 : Ws1;
    const float* a = which ? ar1 : al1;
#pragma unroll
    for (int kc = 0; kc < 2; ++kc) {
      int k = kc * 256 + t;
      float acc = 0.f;
      for (int d = 0; d < 128; ++d)
        acc = fmaf(a[h * 128 + d], W[(size_t)(h * 128 + d) * 512 + k], acc);
      wlr1[which * 2048 + h * 512 + k] = acc;
    }
  } else if (b < 25) {
    int idx = b - 17, which = idx >> 2, h = idx & 3;
    const float* W = which ? Wd2 : Ws2;
    const float* a = which ? ar2 : al2;
#pragma unroll
    for (int kc = 0; kc < 2; ++kc) {
      int k = kc * 256 + t;
      float acc = 0.f;
      for (int d = 0; d < 47; ++d)
        acc = fmaf(a[h * 47 + d], W[(size_t)(h * 47 + d) * 512 + k], acc);
      wlr2[which * 2048 + h * 512 + k] = acc;
    }
  }
  const int n0 = 512 * 256, n1 = 512 * 512, n2 = 188 * 512;
  for (int i = gid; i < n0 + n1 + n2; i += gridDim.x * 256) {
    if (i < n0) B0[i] = f2b(Ws0[i]);
    else if (i < n0 + n1) B1[i - n0] = f2b(Ws1[i - n0]);
    else B2[i - n0 - n1] = f2b(Ws2[i - n0 - n1]);
  }
}

__global__ __launch_bounds__(128) void k_scanA(const int* __restrict__ cnt,
                                               int* __restrict__ S,
                                               int* __restrict__ btot, int n) {
  __shared__ int wt[2];
  int c = blockIdx.x, t = threadIdx.x, lane = t & 63, w = t >> 6;
  int g = c * 128 + t;
  int v = (g < n) ? cnt[g] : 0;
  int incl = v;
  for (int off = 1; off < 64; off <<= 1) {
    int u = __shfl_up(incl, off);
    if (lane >= off) incl += u;
  }
  if (lane == 63) wt[w] = incl;
  __syncthreads();
  int base = (w == 1) ? wt[0] : 0;
  if (g < n) S[g] = incl - v + base;
  if (t == 127) btot[c] = wt[0] + wt[1];
}

__global__ __launch_bounds__(256) void k_scanB(const int* __restrict__ btot,
                                               int* __restrict__ S, int n, int etot) {
  __shared__ int tv[256];
  int c = blockIdx.x, t = threadIdx.x;
  int own = (t < NCH) ? btot[t] : 0;
  tv[t] = own;
  __syncthreads();
  for (int off = 1; off < 256; off <<= 1) {
    int u = (t >= off) ? tv[t - off] : 0;
    __syncthreads();
    tv[t] += u;
    __syncthreads();
  }
  int base = tv[c] - btot[c];
  int g = c * 128 + (t & 127);
  if (t < 128 && g < n) S[g] += base;
  if (c == 0 && t == 255) S[n] = etot;
}

__global__ void k_scatter_all(
    const int* __restrict__ s0, const int* __restrict__ d0,
    const int* __restrict__ s1, const int* __restrict__ d1,
    const int* __restrict__ s2, const int* __restrict__ d2,
    const int* __restrict__ S, const int* __restrict__ r,
    int* __restrict__ cvAll) {
  int g = blockIdx.x * 256 + threadIdx.x;
  if (g >= ETOT) return;
  int goff, dv, sv;
  if (g < E0) { goff = 0; dv = d0[g]; sv = s0[g]; }
  else if (g < E0 + E1) { int e = g - E0; goff = ND0; dv = d1[e]; sv = s1[e]; }
  else { int e = g - E0 - E1; goff = ND0 + ND1; dv = d2[e]; sv = s2[e]; }
  cvAll[S[goff + dv] + r[g]] = sv;
}

// ---------------- per-layer feature kernels ----------------

// L0 dot: MFMA with DIRECT-GLOBAL A fragments (fp32 -> bf16 in regs).
// One barrier (B-table staging); no As LDS. Bitwise-identical to staged form.
__global__ __launch_bounds__(256) void k_dotc_mfma(
    const float* __restrict__ x, const unsigned short* __restrict__ wlrb,
    float* __restrict__ ell, float* __restrict__ err, int Ns, int Nd) {
  __shared__ unsigned short Bs[16 * 264];
  const int tid = threadIdx.x;
  const int w = tid >> 6, lane = tid & 63;
  const int bm = blockIdx.x * 128;
  for (int i = tid; i < 16 * 264; i += 256) Bs[i] = wlrb[i];
  __syncthreads();
  const int kf = (lane >> 4) * 8;
  int rowA = bm + w * 32 + (lane & 15);
  int gm0 = rowA < Ns ? rowA : Ns - 1;
  int gm1 = (rowA + 16) < Ns ? (rowA + 16) : Ns - 1;
  const float* a0p = x + (size_t)gm0 * 256;
  const float* a1p = x + (size_t)gm1 * 256;
  const unsigned short* bp = &Bs[(lane & 15) * 264];
  f32x4 acc[2] = {};
#pragma unroll
  for (int step = 0; step < 8; ++step) {
    int col = (step >> 1) * 64 + (step & 1) * 32 + kf;
    float4 f0a = *reinterpret_cast<const float4*>(a0p + col);
    float4 f0b = *reinterpret_cast<const float4*>(a0p + col + 4);
    float4 f1a = *reinterpret_cast<const float4*>(a1p + col);
    float4 f1b = *reinterpret_cast<const float4*>(a1p + col + 4);
    bf8_t a0, a1;
    a0[0] = (short)f2b(f0a.x); a0[1] = (short)f2b(f0a.y);
    a0[2] = (short)f2b(f0a.z); a0[3] = (short)f2b(f0a.w);
    a0[4] = (short)f2b(f0b.x); a0[5] = (short)f2b(f0b.y);
    a0[6] = (short)f2b(f0b.z); a0[7] = (short)f2b(f0b.w);
    a1[0] = (short)f2b(f1a.x); a1[1] = (short)f2b(f1a.y);
    a1[2] = (short)f2b(f1a.z); a1[3] = (short)f2b(f1a.w);
    a1[4] = (short)f2b(f1b.x); a1[5] = (short)f2b(f1b.y);
    a1[6] = (short)f2b(f1b.z); a1[7] = (short)f2b(f1b.w);
    bf8_t b0 = *reinterpret_cast<const bf8_t*>(bp + col);
    acc[0] = __builtin_amdgcn_mfma_f32_16x16x32_bf16(a0, b0, acc[0], 0, 0, 0);
    acc[1] = __builtin_amdgcn_mfma_f32_16x16x32_bf16(a1, b0, acc[1], 0, 0, 0);
  }
  int col = lane & 15;
#pragma unroll
  for (int fm = 0; fm < 2; ++fm) {
#pragma unroll
    for (int j = 0; j < 4; ++j) {
      int node = bm + w * 32 + fm * 16 + (lane >> 4) * 4 + j;
      if (node >= Ns) continue;
      float v = acc[fm][j];
      if (col < 4) ell[(size_t)node * 4 + col] = v;
      else if (col < 8 && node < Nd) err[(size_t)node * 4 + (col - 4)] = v;
    }
  }
}

__device__ __forceinline__ void reduce8_store(float v[8], int lane, int node, int Nd,
                                              float* __restrict__ ell,
                                              float* __restrict__ err) {
#pragma unroll
  for (int h = 0; h < 8; ++h) {
    v[h] += __shfl_xor(v[h], 8);
    v[h] += __shfl_xor(v[h], 16);
    v[h] += __shfl_xor(v[h], 32);
  }
  int sel = lane >> 3;
  float t01 = (sel & 1) ? v[1] : v[0];
  float t23 = (sel & 1) ? v[3] : v[2];
  float t45 = (sel & 1) ? v[5] : v[4];
  float t67 = (sel & 1) ? v[7] : v[6];
  float t03 = (sel & 2) ? t23 : t01;
  float t47 = (sel & 2) ? t67 : t45;
  float s   = (sel & 4) ? t47 : t03;
  s += __shfl_xor(s, 1);
  s += __shfl_xor(s, 2);
  s += __shfl_xor(s, 4);
  if ((lane & 7) == 0) {
    if (sel < 4) ell[(size_t)node * 4 + sel] = s;
    else if (node < Nd) err[(size_t)node * 4 + (sel - 4)] = s;
  }
}

__global__ __launch_bounds__(256) void k_dot_bf(
    const unsigned short* __restrict__ Hs, const float* __restrict__ wlr,
    float* __restrict__ ell, float* __restrict__ err, int Ns, int Nd) {
  int node = blockIdx.x * 4 + (threadIdx.x >> 6);
  int lane = threadIdx.x & 63;
  if (node >= Ns) return;
  uint4 raw = *reinterpret_cast<const uint4*>(Hs + (size_t)node * 512 + lane * 8);
  float xv[8];
  xv[0] = b2f(raw.x & 0xffffu); xv[1] = b2f(raw.x >> 16);
  xv[2] = b2f(raw.y & 0xffffu); xv[3] = b2f(raw.y >> 16);
  xv[4] = b2f(raw.z & 0xffffu); xv[5] = b2f(raw.z >> 16);
  xv[6] = b2f(raw.w & 0xffffu); xv[7] = b2f(raw.w >> 16);
  bool nR = node < Nd;
  float v[8];
#pragma unroll
  for (int h = 0; h < 4; ++h) {
    const float* wp = wlr + h * 512 + lane * 8;
    float4 w0 = *reinterpret_cast<const float4*>(wp);
    float4 w1 = *reinterpret_cast<const float4*>(wp + 4);
    v[h] = xv[0]*w0.x + xv[1]*w0.y + xv[2]*w0.z + xv[3]*w0.w +
           xv[4]*w1.x + xv[5]*w1.y + xv[6]*w1.z + xv[7]*w1.w;
    v[4 + h] = 0.f;
    if (nR) {
      const float* wq = wlr + 2048 + h * 512 + lane * 8;
      float4 u0 = *reinterpret_cast<const float4*>(wq);
      float4 u1 = *reinterpret_cast<const float4*>(wq + 4);
      v[4 + h] = xv[0]*u0.x + xv[1]*u0.y + xv[2]*u0.z + xv[3]*u0.w +
                 xv[4]*u1.x + xv[5]*u1.y + xv[6]*u1.z + xv[7]*u1.w;
    }
  }
  reduce8_store(v, lane, node, Nd, ell, err);
}

// Unified gather: one WAVE per dst node, 4 nodes per block, barrier-free.
template <int FIN, bool F32>
__global__ __launch_bounds__(256) void k_gather4(
    const void* __restrict__ Hv, const float* __restrict__ ell,
    const float* __restrict__ err, const int* __restrict__ rowptr,
    const int* __restrict__ colv, unsigned short* __restrict__ Z, int Nd) {
  constexpr int CPL = F32 ? 4 : 8;
  constexpr int CAP = 256;
  __shared__ float4 esm_all[4][CAP];
  __shared__ int csm_all[4][CAP];
  int w = threadIdx.x >> 6, lane = threadIdx.x & 63;
  int n = blockIdx.x * 4 + w;
  if (n >= Nd) return;
  float4* esm = esm_all[w];
  int* csm = csm_all[w];
  int beg = rowptr[n], cnt = rowptr[n + 1] - beg;
  float4 er4 = *reinterpret_cast<const float4*>(err + (size_t)n * 4);
  float m0 = -INFINITY, m1 = -INFINITY, m2 = -INFINITY, m3 = -INFINITY;
  for (int i = lane; i < cnt; i += 64) {
    int c = colv[beg + i];
    float4 el4 = *reinterpret_cast<const float4*>(ell + (size_t)c * 4);
    float4 e4;
    e4.x = lrelu(el4.x + er4.x); e4.y = lrelu(el4.y + er4.y);
    e4.z = lrelu(el4.z + er4.z); e4.w = lrelu(el4.w + er4.w);
    if (i < CAP) { csm[i] = c; esm[i] = e4; }
    m0 = fmaxf(m0, e4.x); m1 = fmaxf(m1, e4.y);
    m2 = fmaxf(m2, e4.z); m3 = fmaxf(m3, e4.w);
  }
  for (int off = 32; off > 0; off >>= 1) {
    m0 = fmaxf(m0, __shfl_xor(m0, off));
    m1 = fmaxf(m1, __shfl_xor(m1, off));
    m2 = fmaxf(m2, __shfl_xor(m2, off));
    m3 = fmaxf(m3, __shfl_xor(m3, off));
  }
  __builtin_amdgcn_sched_barrier(0);
  float s0 = 0.f, s1 = 0.f, s2 = 0.f, s3 = 0.f;
  float acc[4][CPL] = {};

  auto loadrow = [&](int c, float xv[CPL]) {
    if constexpr (F32) {
      float4 a = *reinterpret_cast<const float4*>(
          (const float*)Hv + (size_t)c * FIN + lane * 4);
      xv[0] = a.x; xv[1] = a.y; xv[2] = a.z; xv[3] = a.w;
    } else {
      uint4 raw = *reinterpret_cast<const uint4*>(
          (const unsigned short*)Hv + (size_t)c * FIN + lane * 8);
      xv[0] = b2f(raw.x & 0xffffu); xv[1] = b2f(raw.x >> 16);
      xv[2] = b2f(raw.y & 0xffffu); xv[3] = b2f(raw.y >> 16);
      xv[4] = b2f(raw.z & 0xffffu); xv[5] = b2f(raw.z >> 16);
      xv[6] = b2f(raw.w & 0xffffu); xv[7] = b2f(raw.w >> 16);
    }
  };
  auto accum = [&](float4 w4, const float xv[CPL]) {
    s0 += w4.x; s1 += w4.y; s2 += w4.z; s3 += w4.w;
#pragma unroll
    for (int c2 = 0; c2 < CPL; ++c2) {
      acc[0][c2] = fmaf(w4.x, xv[c2], acc[0][c2]);
      acc[1][c2] = fmaf(w4.y, xv[c2], acc[1][c2]);
      acc[2][c2] = fmaf(w4.z, xv[c2], acc[2][c2]);
      acc[3][c2] = fmaf(w4.w, xv[c2], acc[3][c2]);
    }
  };

  if (cnt <= CAP) {
    for (int i = lane; i < cnt; i += 64) {
      float4 e = esm[i];
      esm[i] = make_float4(__expf(e.x - m0), __expf(e.y - m1),
                           __expf(e.z - m2), __expf(e.w - m3));
    }
    __builtin_amdgcn_sched_barrier(0);
    int j = 0;
    for (; j + 2 <= cnt; j += 2) {
      int c0 = csm[j], c1 = csm[j + 1];
      float4 wa = esm[j], wb = esm[j + 1];
      float xa[CPL], xb[CPL];
      loadrow(c0, xa);
      loadrow(c1, xb);
      accum(wa, xa);
      accum(wb, xb);
    }
    if (j < cnt) {
      float xa[CPL];
      loadrow(csm[j], xa);
      accum(esm[j], xa);
    }
  } else {
    for (int j = 0; j < cnt; ++j) {
      int c = colv[beg + j];
      float4 el4 = *reinterpret_cast<const float4*>(ell + (size_t)c * 4);
      float4 w4;
      w4.x = __expf(lrelu(el4.x + er4.x) - m0);
      w4.y = __expf(lrelu(el4.y + er4.y) - m1);
      w4.z = __expf(lrelu(el4.z + er4.z) - m2);
      w4.w = __expf(lrelu(el4.w + er4.w) - m3);
      float xa[CPL];
      loadrow(c, xa);
      accum(w4, xa);
    }
  }
  float inv[4];
  inv[0] = 1.f / fmaxf(s0, 1e-9f); inv[1] = 1.f / fmaxf(s1, 1e-9f);
  inv[2] = 1.f / fmaxf(s2, 1e-9f); inv[3] = 1.f / fmaxf(s3, 1e-9f);
#pragma unroll
  for (int h = 0; h < 4; ++h) {
    if constexpr (F32) {
      ushort4 o;
      o.x = f2b(acc[h][0] * inv[h]); o.y = f2b(acc[h][1] * inv[h]);
      o.z = f2b(acc[h][2] * inv[h]); o.w = f2b(acc[h][3] * inv[h]);
      *reinterpret_cast<ushort4*>(Z + (size_t)n * 4 * FIN + h * FIN + lane * 4) = o;
    } else {
      uint4 o;
      o.x = bpack(acc[h][0] * inv[h], acc[h][1] * inv[h]);
      o.y = bpack(acc[h][2] * inv[h], acc[h][3] * inv[h]);
      o.z = bpack(acc[h][4] * inv[h], acc[h][5] * inv[h]);
      o.w = bpack(acc[h][6] * inv[h], acc[h][7] * inv[h]);
      *reinterpret_cast<uint4*>(Z + (size_t)n * 4 * FIN + h * FIN + lane * 8) = o;
    }
  }
}

// L0 GEMM: K=256, N=128. Full B panel LDS-resident (ONE barrier), direct-A.
__global__ __launch_bounds__(256) void k_gemm_l0(
    const unsigned short* __restrict__ Zb, const unsigned short* __restrict__ Wb,
    const float* __restrict__ bias, unsigned short* __restrict__ out, int M) {
  __shared__ unsigned short Bs[4 * 128 * 64];
  const int tid = threadIdx.x;
  const int w = tid >> 6, lane = tid & 63;
  const int h = blockIdx.z;
  const int bm = blockIdx.x * 128;
  const unsigned short* Ag = Zb + (size_t)h * 256;
  const unsigned short* Bg = Wb + (size_t)h * 128 * 256;
  const int lrow = lane >> 3;
  const int gseg = (lane & 7) ^ lrow;
#pragma unroll
  for (int i = 0; i < 16; ++i) {
    int cidx = w * 16 + i;
    int kb = cidx >> 4, ch = cidx & 15;
    int row = ch * 8 + lrow;
    gload16(Bg + (size_t)row * 256 + kb * 64 + gseg * 8, Bs + kb * 8192 + ch * 512);
  }
  __syncthreads();

  f32x4 acc[2][8];
#pragma unroll
  for (int i = 0; i < 2; ++i)
#pragma unroll
    for (int j = 0; j < 8; ++j) acc[i][j] = (f32x4){0.f, 0.f, 0.f, 0.f};

  const int colsel = lane >> 4;
  int rowA = bm + w * 32 + (lane & 15);
  int gm0 = rowA < M ? rowA : M - 1;
  int gm1 = (rowA + 16) < M ? (rowA + 16) : M - 1;
#pragma unroll
  for (int step = 0; step < 8; ++step) {
    int kb = step >> 1, ks = step & 1;
    int kcol = kb * 64 + ks * 32 + colsel * 8;
    bf8_t a0 = *reinterpret_cast<const bf8_t*>(Ag + (size_t)gm0 * 1024 + kcol);
    bf8_t a1 = *reinterpret_cast<const bf8_t*>(Ag + (size_t)gm1 * 1024 + kcol);
    int cs = ((((ks << 2) + colsel) ^ (lane & 7)) << 3);
#pragma unroll
    for (int fn = 0; fn < 8; ++fn) {
      bf8_t bf = *reinterpret_cast<const bf8_t*>(
          Bs + kb * 8192 + (fn * 16 + (lane & 15)) * 64 + cs);
      acc[0][fn] = __builtin_amdgcn_mfma_f32_16x16x32_bf16(a0, bf, acc[0][fn], 0, 0, 0);
      acc[1][fn] = __builtin_amdgcn_mfma_f32_16x16x32_bf16(a1, bf, acc[1][fn], 0, 0, 0);
    }
  }
#pragma unroll
  for (int fm = 0; fm < 2; ++fm) {
#pragma unroll
    for (int fn = 0; fn < 8; ++fn) {
      int colb = fn * 16 + (lane & 15);
      float bv = bias[h * 128 + colb];
#pragma unroll
      for (int j = 0; j < 4; ++j) {
        int rowb = bm + w * 32 + fm * 16 + (lane >> 4) * 4 + j;
        if (rowb >= M) continue;
        float v = acc[fm][fn][j] + bv;
        v = v > 0.f ? v : (__expf(v) - 1.f);
        out[(size_t)rowb * 512 + h * 128 + colb] = f2b(v);
      }
    }
  }
}

// L1 GEMM: K=512, N=128. Split-K halves, B half LDS-resident, direct-A.
__global__ __launch_bounds__(256) void k_gemm_l1(
    const unsigned short* __restrict__ Zb, const unsigned short* __restrict__ Wb,
    const float* __restrict__ bias, unsigned short* __restrict__ out, int M) {
  __shared__ unsigned short Bs[4 * 128 * 64];  // 64KB: one K-half of B
  const int tid = threadIdx.x;
  const int w = tid >> 6, lane = tid & 63;
  const int h = blockIdx.z;
  const int bm = blockIdx.x * 128;
  const unsigned short* Ag = Zb + (size_t)h * 512;        // lda = 2048
  const unsigned short* Bg = Wb + (size_t)h * 128 * 512;  // [128][512]
  const int lrow = lane >> 3;
  const int gseg = (lane & 7) ^ lrow;
  const int colsel = lane >> 4;
  int rowA = bm + w * 32 + (lane & 15);
  int gm0 = rowA < M ? rowA : M - 1;
  int gm1 = (rowA + 16) < M ? (rowA + 16) : M - 1;

  f32x4 acc[2][8];
#pragma unroll
  for (int i = 0; i < 2; ++i)
#pragma unroll
    for (int j = 0; j < 8; ++j) acc[i][j] = (f32x4){0.f, 0.f, 0.f, 0.f};

#pragma unroll
  for (int half = 0; half < 2; ++half) {
    if (half) __syncthreads();  // prev half's Bs reads done
#pragma unroll
    for (int i = 0; i < 16; ++i) {
      int cidx = w * 16 + i;
      int kb = cidx >> 4, ch = cidx & 15;
      int row = ch * 8 + lrow;
      gload16(Bg + (size_t)row * 512 + half * 256 + kb * 64 + gseg * 8,
              Bs + kb * 8192 + ch * 512);
    }
    __syncthreads();
#pragma unroll
    for (int step = 0; step < 8; ++step) {
      int kb = step >> 1, ks = step & 1;
      int kcol = half * 256 + kb * 64 + ks * 32 + colsel * 8;
      bf8_t a0 = *reinterpret_cast<const bf8_t*>(Ag + (size_t)gm0 * 2048 + kcol);
      bf8_t a1 = *reinterpret_cast<const bf8_t*>(Ag + (size_t)gm1 * 2048 + kcol);
      int cs = ((((ks << 2) + colsel) ^ (lane & 7)) << 3);
#pragma unroll
      for (int fn = 0; fn < 8; ++fn) {
        bf8_t bf = *reinterpret_cast<const bf8_t*>(
            Bs + kb * 8192 + (fn * 16 + (lane & 15)) * 64 + cs);
        acc[0][fn] = __builtin_amdgcn_mfma_f32_16x16x32_bf16(a0, bf, acc[0][fn], 0, 0, 0);
        acc[1][fn] = __builtin_amdgcn_mfma_f32_16x16x32_bf16(a1, bf, acc[1][fn], 0, 0, 0);
      }
    }
  }
#pragma unroll
  for (int fm = 0; fm < 2; ++fm) {
#pragma unroll
    for (int fn = 0; fn < 8; ++fn) {
      int colb = fn * 16 + (lane & 15);
      float bv = bias[h * 128 + colb];
#pragma unroll
      for (int j = 0; j < 4; ++j) {
        int rowb = bm + w * 32 + fm * 16 + (lane >> 4) * 4 + j;
        if (rowb >= M) continue;
        float v = acc[fm][fn][j] + bv;
        v = v > 0.f ? v : (__expf(v) - 1.f);
        out[(size_t)rowb * 512 + h * 128 + colb] = f2b(v);
      }
    }
  }
}

// bf16 MFMA GEMM (proven; used for L2)
template <int BN, bool ACT, bool OUTBF>
__global__ __launch_bounds__(256) void k_gemm_mfma(
    const unsigned short* __restrict__ Zb, const unsigned short* __restrict__ Wb,
    const float* __restrict__ bias, void* __restrict__ outv,
    int M, int N, int K) {
  constexpr int FN = BN / 16;
  constexpr int AI = 4;
  constexpr int BI = BN / 32;
  int h = blockIdx.z;
  __shared__ unsigned short As[128 * 64];
  __shared__ unsigned short Bs[BN * 64];
  const int tid = threadIdx.x;
  const int w = tid >> 6, lane = tid & 63;
  const int bm = blockIdx.x * 128, bn = blockIdx.y * BN;
  const int lda = 4 * K;
  const unsigned short* Ag = Zb + (size_t)h * K;
  const unsigned short* Bg = Wb + (size_t)h * N * K;
  const int lrow = lane >> 3;
  const int gseg = (lane & 7) ^ lrow;
  f32x4 acc[2][FN];
#pragma unroll
  for (int i = 0; i < 2; ++i)
#pragma unroll
    for (int j = 0; j < FN; ++j) acc[i][j] = (f32x4){0.f, 0.f, 0.f, 0.f};

  for (int k0 = 0; k0 < K; k0 += 64) {
    __syncthreads();
#pragma unroll
    for (int i = 0; i < AI; ++i) {
      int ch = w * AI + i;
      int row = ch * 8 + lrow;
      int gm = bm + row; gm = gm < M ? gm : M - 1;
      gload16(Ag + (size_t)gm * lda + k0 + gseg * 8, As + ch * 512);
    }
#pragma unroll
    for (int i = 0; i < BI; ++i) {
      int ch = w * BI + i;
      int row = ch * 8 + lrow;
      int gn = bn + row; gn = gn < N ? gn : N - 1;
      gload16(Bg + (size_t)gn * K + k0 + gseg * 8, Bs + ch * 512);
    }
    __syncthreads();
    const int ra = w * 32 + (lane & 15);
#pragma unroll
    for (int ks = 0; ks < 2; ++ks) {
      int cs = ((((ks << 2) + (lane >> 4)) ^ (lane & 7)) << 3);
      bf8_t a0 = *reinterpret_cast<const bf8_t*>(As + ra * 64 + cs);
      bf8_t a1 = *reinterpret_cast<const bf8_t*>(As + (ra + 16) * 64 + cs);
#pragma unroll
      for (int fn = 0; fn < FN; ++fn) {
        bf8_t bf = *reinterpret_cast<const bf8_t*>(Bs + (fn * 16 + (lane & 15)) * 64 + cs);
        acc[0][fn] = __builtin_amdgcn_mfma_f32_16x16x32_bf16(a0, bf, acc[0][fn], 0, 0, 0);
        acc[1][fn] = __builtin_amdgcn_mfma_f32_16x16x32_bf16(a1, bf, acc[1][fn], 0, 0, 0);
      }
    }
  }
  int ldo = 4 * N;
#pragma unroll
  for (int fm = 0; fm < 2; ++fm) {
#pragma unroll
    for (int fn = 0; fn < FN; ++fn) {
      int colb = bn + fn * 16 + (lane & 15);
      if (colb >= N) continue;
      float bv = bias[h * N + colb];
#pragma unroll
      for (int j = 0; j < 4; ++j) {
        int rowb = bm + w * 32 + fm * 16 + (lane >> 4) * 4 + j;
        if (rowb >= M) continue;
        float v = acc[fm][fn][j] + bv;
        if (ACT) v = v > 0.f ? v : (__expf(v) - 1.f);
        size_t off = (size_t)rowb * ldo + (size_t)h * N + colb;
        if (OUTBF) ((unsigned short*)outv)[off] = f2b(v);
        else ((float*)outv)[off] = v;
      }
    }
  }
}

// mean over 4 heads (C=47) + log_softmax; one wave per node
__global__ __launch_bounds__(256) void k_mean_lsm(const float* __restrict__ rst2,
                                                  float* __restrict__ out, int Nd) {
  int node = blockIdx.x * 4 + (threadIdx.x >> 6);
  int lane = threadIdx.x & 63;
  if (node >= Nd) return;
  const float* r = rst2 + (size_t)node * 188;
  float vv = 0.f;
  if (lane < 47)
    vv = 0.25f * (r[lane] + r[47 + lane] + r[94 + lane] + r[141 + lane]);
  float m = (lane < 47) ? vv : -INFINITY;
  for (int off = 32; off > 0; off >>= 1) m = fmaxf(m, __shfl_xor(m, off));
  float ex = (lane < 47) ? __expf(vv - m) : 0.f;
  float ss = ex;
  for (int off = 32; off > 0; off >>= 1) ss += __shfl_xor(ss, off);
  if (lane < 47) out[(size_t)node * 47 + lane] = vv - m - logf(ss);
}

extern "C" void kernel_launch(void* const* d_in, const int* in_sizes, int n_in,
                              void* d_out, int out_size, void* d_ws, size_t ws_size,
                              hipStream_t stream) {
  (void)in_sizes; (void)n_in; (void)out_size; (void)ws_size;
  const float* x = (const float*)d_in[0];
  const int* srcs[3] = {(const int*)d_in[1], (const int*)d_in[3], (const int*)d_in[5]};
  const int* dsts[3] = {(const int*)d_in[2], (const int*)d_in[4], (const int*)d_in[6]};
  const float* Wsrc[3] = {(const float*)d_in[7], (const float*)d_in[12], (const float*)d_in[17]};
  const float* Wdst[3] = {(const float*)d_in[8], (const float*)d_in[13], (const float*)d_in[18]};
  const float* al[3]   = {(const float*)d_in[9], (const float*)d_in[14], (const float*)d_in[19]};
  const float* ar[3]   = {(const float*)d_in[10], (const float*)d_in[15], (const float*)d_in[20]};
  const float* bb[3]   = {(const float*)d_in[11], (const float*)d_in[16], (const float*)d_in[21]};

  char* p = (char*)d_ws;
  auto alloc = [&](size_t bytes) -> void* {
    void* r = (void*)p;
    p += (bytes + 255) & ~(size_t)255;
    return r;
  };
  unsigned short* zbf = (unsigned short*)alloc((size_t)25000 * 1024 * 2);
  unsigned short* h1  = (unsigned short*)alloc((size_t)25000 * 512 * 2);
  unsigned short* h2  = (unsigned short*)alloc((size_t)6000 * 512 * 2);
  float* rst2   = (float*)alloc((size_t)1024 * 188 * 4);
  unsigned short* Wb0 = (unsigned short*)alloc((size_t)512 * 256 * 2);
  unsigned short* Wb1 = (unsigned short*)alloc((size_t)512 * 512 * 2);
  unsigned short* Wb2 = (unsigned short*)alloc((size_t)188 * 512 * 2);
  float* ell    = (float*)alloc((size_t)150000 * 4 * 4);
  float* err    = (float*)alloc((size_t)25000 * 4 * 4);
  int* cntAll   = (int*)alloc((size_t)NTOT * 4);
  int* Sarr     = (int*)alloc((size_t)(NTOT + 8) * 4);
  int* btot     = (int*)alloc((size_t)((NCH + 7) & ~7) * 4);
  int* r_all    = (int*)alloc((size_t)ETOT * 4);
  int* cvAll    = (int*)alloc((size_t)ETOT * 4);
  unsigned short* wlrb = (unsigned short*)alloc((size_t)16 * 264 * 2);
  float* wlr1   = (float*)alloc((size_t)8 * 512 * 4);
  float* wlr2   = (float*)alloc((size_t)8 * 512 * 4);

  hipMemsetAsync(cntAll, 0, (size_t)NTOT * 4, stream);
  k_prep_count<<<(ETOT + 255) / 256, 256, 0, stream>>>(
      dsts[0], dsts[1], dsts[2], cntAll, r_all,
      Wsrc[0], Wdst[0], al[0], ar[0], Wsrc[1], Wdst[1], al[1], ar[1],
      Wsrc[2], Wdst[2], al[2], ar[2], wlrb, wlr1, wlr2, Wb0, Wb1, Wb2);
  k_scanA<<<NCH, 128, 0, stream>>>(cntAll, Sarr, btot, NTOT);
  k_scanB<<<NCH, 256, 0, stream>>>(btot, Sarr, NTOT, ETOT);
  k_scatter_all<<<(ETOT + 255) / 256, 256, 0, stream>>>(
      srcs[0], dsts[0], srcs[1], dsts[1], srcs[2], dsts[2], Sarr, r_all, cvAll);

  const unsigned short* Hbf[3] = {nullptr, h1, h2};
  const unsigned short* Wbf[3] = {Wb0, Wb1, Wb2};
  const float* wlrs[3] = {nullptr, wlr1, wlr2};
  const int noff[3] = {0, ND0, ND0 + ND1};

  for (int l = 0; l < 3; ++l) {
    int Ns = L_NS[l], Nd = L_ND[l];
    if (l == 0) {
      k_dotc_mfma<<<(Ns + 127) / 128, 256, 0, stream>>>(x, wlrb, ell, err, Ns, Nd);
      k_gather4<256, true><<<(Nd + 3) / 4, 256, 0, stream>>>(
          x, ell, err, Sarr + noff[l], cvAll, zbf, Nd);
    } else {
      k_dot_bf<<<(Ns + 3) / 4, 256, 0, stream>>>(Hbf[l], wlrs[l], ell, err, Ns, Nd);
      k_gather4<512, false><<<(Nd + 3) / 4, 256, 0, stream>>>(
          Hbf[l], ell, err, Sarr + noff[l], cvAll, zbf, Nd);
    }
    if (l == 0) {
      dim3 g((Nd + 127) / 128, 1, 4);
      k_gemm_l0<<<g, 256, 0, stream>>>(zbf, Wbf[l], bb[l], h1, Nd);
    } else if (l == 1) {
      dim3 g((Nd + 127) / 128, 1, 4);
      k_gemm_l1<<<g, 256, 0, stream>>>(zbf, Wbf[l], bb[l], h2, Nd);
    } else {
      dim3 g((Nd + 127) / 128, 1, 4);
      k_gemm_mfma<64, false, false><<<g, 256, 0, stream>>>(zbf, Wbf[l], bb[l], rst2, Nd, 47, 512);
    }
  }
  k_mean_lsm<<<(1024 + 3) / 4, 256, 0, stream>>>(rst2, (float*)d_out, 1024);
}